// Round 1
// baseline (596.155 us; speedup 1.0000x reference)
//
#include <hip/hip_runtime.h>

#define LEAKY 0.2f

// ---------------- counting sort of edges by destination ----------------

__global__ void count_dst(const int* __restrict__ dst, int* __restrict__ cnt, int E) {
    int i = blockIdx.x * blockDim.x + threadIdx.x;
    int stride = gridDim.x * blockDim.x;
    for (int e = i; e < E; e += stride)
        atomicAdd(&cnt[dst[e]], 1);
}

__global__ __launch_bounds__(1024) void scan_chunk(const int* __restrict__ cnt,
                                                   int* __restrict__ incl,
                                                   int* __restrict__ bsum, int n) {
    __shared__ int s[1024];
    int tid = threadIdx.x;
    int i = blockIdx.x * 1024 + tid;
    int v = (i < n) ? cnt[i] : 0;
    s[tid] = v;
    __syncthreads();
    for (int off = 1; off < 1024; off <<= 1) {
        int add = (tid >= off) ? s[tid - off] : 0;
        __syncthreads();
        s[tid] += add;
        __syncthreads();
    }
    incl[i] = s[tid];
    if (tid == 1023) bsum[blockIdx.x] = s[1023];
}

__global__ void scan_bsum(const int* __restrict__ bsum, int* __restrict__ bsumEx, int nb) {
    if (threadIdx.x == 0 && blockIdx.x == 0) {
        int run = 0;
        for (int j = 0; j < nb; ++j) { int t = bsum[j]; bsumEx[j] = run; run += t; }
    }
}

__global__ void finalize_rowptr(const int* __restrict__ cnt, const int* __restrict__ incl,
                                const int* __restrict__ bsumEx, int* __restrict__ rowptr,
                                int* __restrict__ woff, int n) {
    int i = blockIdx.x * blockDim.x + threadIdx.x;
    int stride = gridDim.x * blockDim.x;
    for (int j = i; j < n; j += stride) {
        int rp = incl[j] - cnt[j] + bsumEx[j >> 10];
        rowptr[j] = rp;
        woff[j] = rp;
        if (j == n - 1) rowptr[n] = incl[j] + bsumEx[j >> 10];
    }
}

__global__ void scatter_edges(const int* __restrict__ src, const int* __restrict__ dst,
                              int* __restrict__ woff, int* __restrict__ ssrc, int E) {
    int i = blockIdx.x * blockDim.x + threadIdx.x;
    int stride = gridDim.x * blockDim.x;
    for (int e = i; e < E; e += stride) {
        int d = dst[e];
        int pos = atomicAdd(&woff[d], 1);
        ssrc[pos] = src[e];
    }
}

// ---------------- dual GEMM: xl = x@Wl+bl, xr = x@Wr+br ----------------
// Block: 256 threads, tile = 32 rows x 128 cols, x tile staged in LDS,
// W read through L1/L2 (64-128 KB, fully cached, coalesced per wave).

template<int F>
__global__ __launch_bounds__(256) void gemm_dual(
    const float* __restrict__ x,
    const float* __restrict__ Wl, const float* __restrict__ bl,
    const float* __restrict__ Wr, const float* __restrict__ br,
    float* __restrict__ xl, float* __restrict__ xr, int n)
{
    __shared__ float xs[32][F];
    const int t = threadIdx.x;
    const int row0 = blockIdx.x * 32;
    constexpr int F4 = F / 4;
    const float4* xg = reinterpret_cast<const float4*>(x);
    float4* xs4 = reinterpret_cast<float4*>(&xs[0][0]);
    for (int i = t; i < 32 * F4; i += 256) {
        int r = i / F4, kk = i % F4;
        int gr = row0 + r;
        float4 v = make_float4(0.f, 0.f, 0.f, 0.f);
        if (gr < n) v = xg[(size_t)gr * F4 + kk];
        xs4[i] = v;
    }
    __syncthreads();

    const int col = t & 127;
    const int rh = t >> 7;   // 0 or 1: which half of the 32 rows
    float accl[16], accr[16];
#pragma unroll
    for (int r = 0; r < 16; ++r) { accl[r] = 0.f; accr[r] = 0.f; }

    for (int k = 0; k < F; k += 4) {
        float wl0 = Wl[(k + 0) * 128 + col], wl1 = Wl[(k + 1) * 128 + col];
        float wl2 = Wl[(k + 2) * 128 + col], wl3 = Wl[(k + 3) * 128 + col];
        float wr0 = Wr[(k + 0) * 128 + col], wr1 = Wr[(k + 1) * 128 + col];
        float wr2 = Wr[(k + 2) * 128 + col], wr3 = Wr[(k + 3) * 128 + col];
#pragma unroll
        for (int r = 0; r < 16; ++r) {
            const float4 xv = *reinterpret_cast<const float4*>(&xs[r * 2 + rh][k]);
            accl[r] += xv.x * wl0 + xv.y * wl1 + xv.z * wl2 + xv.w * wl3;
            accr[r] += xv.x * wr0 + xv.y * wr1 + xv.z * wr2 + xv.w * wr3;
        }
    }

    const float blv = bl[col], brv = br[col];
#pragma unroll
    for (int r = 0; r < 16; ++r) {
        int gr = row0 + r * 2 + rh;
        if (gr < n) {
            xl[(size_t)gr * 128 + col] = accl[r] + blv;
            xr[(size_t)gr * 128 + col] = accr[r] + brv;
        }
    }
}

// ---------------- fused per-destination GATv2 aggregation ----------------
// One node per 128 threads (2 waves); thread t owns channel t (h=t>>5,c=t&31).
// Per incoming edge: gather xl[src] (coalesced), score via 32-lane butterfly
// reduce, exp (no max subtraction needed: scores are O(1), never overflow),
// accumulate numerator and denominator in registers. No atomics.

__global__ __launch_bounds__(256) void gat_agg(
    const float* __restrict__ xl, const float* __restrict__ xr,
    const float* __restrict__ att, const float* __restrict__ bias,
    const int* __restrict__ rowptr, const int* __restrict__ ssrc,
    float* __restrict__ out, int n)
{
    int node = blockIdx.x * 2 + (threadIdx.x >> 7);
    if (node >= n) return;
    int t = threadIdx.x & 127;

    float a   = att[t];
    float xrv = xr[(size_t)node * 128 + t];
    float acc = 0.f, den = 0.f;

    // self loop
    {
        float xlv = xl[(size_t)node * 128 + t];
        float v = xlv + xrv;
        float lr = v > 0.f ? v : LEAKY * v;
        float p = lr * a;
#pragma unroll
        for (int off = 16; off >= 1; off >>= 1) p += __shfl_xor(p, off);
        float ex = __expf(p);
        den += ex;
        acc += ex * xlv;
    }

    int beg = rowptr[node], end = rowptr[node + 1];
    for (int i = beg; i < end; ++i) {
        int s = ssrc[i];
        float xlv = xl[(size_t)s * 128 + t];
        float v = xlv + xrv;
        float lr = v > 0.f ? v : LEAKY * v;
        float p = lr * a;
#pragma unroll
        for (int off = 16; off >= 1; off >>= 1) p += __shfl_xor(p, off);
        float ex = __expf(p);
        den += ex;
        acc += ex * xlv;
    }

    float o = acc / den + bias[t];
    out[(size_t)node * 128 + t] = fmaxf(o, 0.f);
}

// ---------------- launch ----------------

extern "C" void kernel_launch(void* const* d_in, const int* in_sizes, int n_in,
                              void* d_out, int out_size, void* d_ws, size_t ws_size,
                              hipStream_t stream)
{
    const float* x     = (const float*)d_in[0];
    const float* Wl1   = (const float*)d_in[1];
    const float* bl1   = (const float*)d_in[2];
    const float* Wr1   = (const float*)d_in[3];
    const float* br1   = (const float*)d_in[4];
    const float* att1  = (const float*)d_in[5];
    const float* bias1 = (const float*)d_in[6];
    const float* Wl2   = (const float*)d_in[7];
    const float* bl2   = (const float*)d_in[8];
    const float* Wr2   = (const float*)d_in[9];
    const float* br2   = (const float*)d_in[10];
    const float* att2  = (const float*)d_in[11];
    const float* bias2 = (const float*)d_in[12];
    const int*   eidx  = (const int*)d_in[13];

    const int n = in_sizes[0] / 64;
    const int E = in_sizes[13] / 2;
    const int* src = eidx;
    const int* dst = eidx + E;

    char* ws = (char*)d_ws;
    size_t off = 0;
    auto alloc = [&](size_t bytes) -> void* {
        void* p = ws + off;
        off = (off + bytes + 255) & ~(size_t)255;
        return p;
    };
    const int nb = (n + 1023) / 1024;
    int* cnt      = (int*)alloc((size_t)n * 4);
    int* incl     = (int*)alloc((size_t)nb * 1024 * 4);
    int* bsum     = (int*)alloc((size_t)nb * 4);
    int* bsumEx   = (int*)alloc((size_t)nb * 4);
    int* rowptr   = (int*)alloc((size_t)(n + 1) * 4);
    int* woff     = (int*)alloc((size_t)n * 4);
    int* ssrc     = (int*)alloc((size_t)E * 4);
    float* xlbuf  = (float*)alloc((size_t)n * 128 * 4);
    float* xrbuf  = (float*)alloc((size_t)n * 128 * 4);
    float* hbuf   = (float*)alloc((size_t)n * 128 * 4);
    float* outp   = (float*)d_out;

    // ---- build CSR by dst (graph fixed: reused by both layers) ----
    hipMemsetAsync(cnt, 0, (size_t)n * 4, stream);
    count_dst<<<512, 256, 0, stream>>>(dst, cnt, E);
    scan_chunk<<<nb, 1024, 0, stream>>>(cnt, incl, bsum, n);
    scan_bsum<<<1, 64, 0, stream>>>(bsum, bsumEx, nb);
    finalize_rowptr<<<(n + 255) / 256, 256, 0, stream>>>(cnt, incl, bsumEx, rowptr, woff, n);
    scatter_edges<<<512, 256, 0, stream>>>(src, dst, woff, ssrc, E);

    // ---- layer 1 ----
    gemm_dual<64><<<(n + 31) / 32, 256, 0, stream>>>(x, Wl1, bl1, Wr1, br1, xlbuf, xrbuf, n);
    gat_agg<<<(n + 1) / 2, 256, 0, stream>>>(xlbuf, xrbuf, att1, bias1, rowptr, ssrc, hbuf, n);

    // ---- layer 2 ----
    gemm_dual<128><<<(n + 31) / 32, 256, 0, stream>>>(hbuf, Wl2, bl2, Wr2, br2, xlbuf, xrbuf, n);
    gat_agg<<<(n + 1) / 2, 256, 0, stream>>>(xlbuf, xrbuf, att2, bias2, rowptr, ssrc, outp, n);
}

// Round 2
// 361.957 us; speedup vs baseline: 1.6470x; 1.6470x over previous
//
#include <hip/hip_runtime.h>

#define LEAKY 0.2f

// ---------------- counting sort of edges by destination ----------------

__global__ void count_dst(const int* __restrict__ dst, int* __restrict__ cnt, int E) {
    int i = blockIdx.x * blockDim.x + threadIdx.x;
    int stride = gridDim.x * blockDim.x;
    for (int e = i; e < E; e += stride)
        atomicAdd(&cnt[dst[e]], 1);
}

__global__ __launch_bounds__(1024) void scan_chunk(const int* __restrict__ cnt,
                                                   int* __restrict__ incl,
                                                   int* __restrict__ bsum, int n) {
    __shared__ int s[1024];
    int tid = threadIdx.x;
    int i = blockIdx.x * 1024 + tid;
    int v = (i < n) ? cnt[i] : 0;
    s[tid] = v;
    __syncthreads();
    for (int off = 1; off < 1024; off <<= 1) {
        int add = (tid >= off) ? s[tid - off] : 0;
        __syncthreads();
        s[tid] += add;
        __syncthreads();
    }
    incl[i] = s[tid];
    if (tid == 1023) bsum[blockIdx.x] = s[1023];
}

__global__ void scan_bsum(const int* __restrict__ bsum, int* __restrict__ bsumEx, int nb) {
    if (threadIdx.x == 0 && blockIdx.x == 0) {
        int run = 0;
        for (int j = 0; j < nb; ++j) { int t = bsum[j]; bsumEx[j] = run; run += t; }
    }
}

__global__ void finalize_rowptr(const int* __restrict__ cnt, const int* __restrict__ incl,
                                const int* __restrict__ bsumEx, int* __restrict__ rowptr,
                                int* __restrict__ woff, int n) {
    int i = blockIdx.x * blockDim.x + threadIdx.x;
    int stride = gridDim.x * blockDim.x;
    for (int j = i; j < n; j += stride) {
        int rp = incl[j] - cnt[j] + bsumEx[j >> 10];
        rowptr[j] = rp;
        woff[j] = rp;
        if (j == n - 1) rowptr[n] = incl[j] + bsumEx[j >> 10];
    }
}

__global__ void scatter_edges(const int* __restrict__ src, const int* __restrict__ dst,
                              int* __restrict__ woff, int* __restrict__ ssrc, int E) {
    int i = blockIdx.x * blockDim.x + threadIdx.x;
    int stride = gridDim.x * blockDim.x;
    for (int e = i; e < E; e += stride) {
        int d = dst[e];
        int pos = atomicAdd(&woff[d], 1);
        ssrc[pos] = src[e];
    }
}

// ---------------- dual GEMM: xl = x@Wl+bl, xr = x@Wr+br ----------------

template<int F>
__global__ __launch_bounds__(256) void gemm_dual(
    const float* __restrict__ x,
    const float* __restrict__ Wl, const float* __restrict__ bl,
    const float* __restrict__ Wr, const float* __restrict__ br,
    float* __restrict__ xl, float* __restrict__ xr, int n)
{
    __shared__ float xs[32][F];
    const int t = threadIdx.x;
    const int row0 = blockIdx.x * 32;
    constexpr int F4 = F / 4;
    const float4* xg = reinterpret_cast<const float4*>(x);
    float4* xs4 = reinterpret_cast<float4*>(&xs[0][0]);
    for (int i = t; i < 32 * F4; i += 256) {
        int r = i / F4, kk = i % F4;
        int gr = row0 + r;
        float4 v = make_float4(0.f, 0.f, 0.f, 0.f);
        if (gr < n) v = xg[(size_t)gr * F4 + kk];
        xs4[i] = v;
    }
    __syncthreads();

    const int col = t & 127;
    const int rh = t >> 7;   // 0 or 1: which half of the 32 rows
    float accl[16], accr[16];
#pragma unroll
    for (int r = 0; r < 16; ++r) { accl[r] = 0.f; accr[r] = 0.f; }

    for (int k = 0; k < F; k += 4) {
        float wl0 = Wl[(k + 0) * 128 + col], wl1 = Wl[(k + 1) * 128 + col];
        float wl2 = Wl[(k + 2) * 128 + col], wl3 = Wl[(k + 3) * 128 + col];
        float wr0 = Wr[(k + 0) * 128 + col], wr1 = Wr[(k + 1) * 128 + col];
        float wr2 = Wr[(k + 2) * 128 + col], wr3 = Wr[(k + 3) * 128 + col];
#pragma unroll
        for (int r = 0; r < 16; ++r) {
            const float4 xv = *reinterpret_cast<const float4*>(&xs[r * 2 + rh][k]);
            accl[r] += xv.x * wl0 + xv.y * wl1 + xv.z * wl2 + xv.w * wl3;
            accr[r] += xv.x * wr0 + xv.y * wr1 + xv.z * wr2 + xv.w * wr3;
        }
    }

    const float blv = bl[col], brv = br[col];
#pragma unroll
    for (int r = 0; r < 16; ++r) {
        int gr = row0 + r * 2 + rh;
        if (gr < n) {
            xl[(size_t)gr * 128 + col] = accl[r] + blv;
            xr[(size_t)gr * 128 + col] = accr[r] + brv;
        }
    }
}

// ---------------- fused per-destination GATv2 aggregation ----------------
// One node per 64-lane WAVE; lane owns channels (2*lane, 2*lane+1) as float2.
// Head h lives in lanes [16h,16h+16): butterfly over offsets 1/2/4/8 reduces
// the 32-channel dot within each head group. Edge loop unrolled x4 so four
// independent 512B gathers + four independent shfl chains are in flight
// (previous version had VGPR=12 => zero ILP, latency-bound at 188us).

__global__ __launch_bounds__(256) void gat_agg(
    const float* __restrict__ xl, const float* __restrict__ xr,
    const float* __restrict__ att, const float* __restrict__ bias,
    const int* __restrict__ rowptr, const int* __restrict__ ssrc,
    float* __restrict__ out, int n)
{
    const int node = blockIdx.x * 4 + (threadIdx.x >> 6);
    if (node >= n) return;
    const int lane = threadIdx.x & 63;

    const float2* __restrict__ xl2 = reinterpret_cast<const float2*>(xl);
    const float2 a2  = *reinterpret_cast<const float2*>(&att[lane * 2]);
    const float2 xrv = *reinterpret_cast<const float2*>(&xr[(size_t)node * 128 + lane * 2]);

    float den = 0.f, acc0 = 0.f, acc1 = 0.f;

#define EDGE(v)                                                       \
    {                                                                 \
        float e0 = (v).x + xrv.x, e1 = (v).y + xrv.y;                 \
        e0 = e0 > 0.f ? e0 : LEAKY * e0;                              \
        e1 = e1 > 0.f ? e1 : LEAKY * e1;                              \
        float p = e0 * a2.x + e1 * a2.y;                              \
        p += __shfl_xor(p, 1);                                        \
        p += __shfl_xor(p, 2);                                        \
        p += __shfl_xor(p, 4);                                        \
        p += __shfl_xor(p, 8);                                        \
        float ex = __expf(p);                                         \
        den  += ex;                                                   \
        acc0 += ex * (v).x;                                           \
        acc1 += ex * (v).y;                                           \
    }

    // self loop
    {
        float2 v = xl2[(size_t)node * 64 + lane];
        EDGE(v);
    }

    int i = rowptr[node];
    const int end = rowptr[node + 1];
    for (; i + 4 <= end; i += 4) {
        int s0 = ssrc[i], s1 = ssrc[i + 1], s2 = ssrc[i + 2], s3 = ssrc[i + 3];
        float2 v0 = xl2[(size_t)s0 * 64 + lane];
        float2 v1 = xl2[(size_t)s1 * 64 + lane];
        float2 v2 = xl2[(size_t)s2 * 64 + lane];
        float2 v3 = xl2[(size_t)s3 * 64 + lane];
        EDGE(v0); EDGE(v1); EDGE(v2); EDGE(v3);
    }
    for (; i < end; ++i) {
        float2 v = xl2[(size_t)ssrc[i] * 64 + lane];
        EDGE(v);
    }
#undef EDGE

    const float rden = 1.f / den;
    float o0 = acc0 * rden + bias[lane * 2];
    float o1 = acc1 * rden + bias[lane * 2 + 1];
    float2 o = make_float2(fmaxf(o0, 0.f), fmaxf(o1, 0.f));
    *reinterpret_cast<float2*>(&out[(size_t)node * 128 + lane * 2]) = o;
}

// ---------------- launch ----------------

extern "C" void kernel_launch(void* const* d_in, const int* in_sizes, int n_in,
                              void* d_out, int out_size, void* d_ws, size_t ws_size,
                              hipStream_t stream)
{
    const float* x     = (const float*)d_in[0];
    const float* Wl1   = (const float*)d_in[1];
    const float* bl1   = (const float*)d_in[2];
    const float* Wr1   = (const float*)d_in[3];
    const float* br1   = (const float*)d_in[4];
    const float* att1  = (const float*)d_in[5];
    const float* bias1 = (const float*)d_in[6];
    const float* Wl2   = (const float*)d_in[7];
    const float* bl2   = (const float*)d_in[8];
    const float* Wr2   = (const float*)d_in[9];
    const float* br2   = (const float*)d_in[10];
    const float* att2  = (const float*)d_in[11];
    const float* bias2 = (const float*)d_in[12];
    const int*   eidx  = (const int*)d_in[13];

    const int n = in_sizes[0] / 64;
    const int E = in_sizes[13] / 2;
    const int* src = eidx;
    const int* dst = eidx + E;

    char* ws = (char*)d_ws;
    size_t off = 0;
    auto alloc = [&](size_t bytes) -> void* {
        void* p = ws + off;
        off = (off + bytes + 255) & ~(size_t)255;
        return p;
    };
    const int nb = (n + 1023) / 1024;
    int* cnt      = (int*)alloc((size_t)n * 4);
    int* incl     = (int*)alloc((size_t)nb * 1024 * 4);
    int* bsum     = (int*)alloc((size_t)nb * 4);
    int* bsumEx   = (int*)alloc((size_t)nb * 4);
    int* rowptr   = (int*)alloc((size_t)(n + 1) * 4);
    int* woff     = (int*)alloc((size_t)n * 4);
    int* ssrc     = (int*)alloc((size_t)E * 4);
    float* xlbuf  = (float*)alloc((size_t)n * 128 * 4);
    float* xrbuf  = (float*)alloc((size_t)n * 128 * 4);
    float* hbuf   = (float*)alloc((size_t)n * 128 * 4);
    float* outp   = (float*)d_out;

    // ---- build CSR by dst (graph fixed: reused by both layers) ----
    hipMemsetAsync(cnt, 0, (size_t)n * 4, stream);
    count_dst<<<512, 256, 0, stream>>>(dst, cnt, E);
    scan_chunk<<<nb, 1024, 0, stream>>>(cnt, incl, bsum, n);
    scan_bsum<<<1, 64, 0, stream>>>(bsum, bsumEx, nb);
    finalize_rowptr<<<(n + 255) / 256, 256, 0, stream>>>(cnt, incl, bsumEx, rowptr, woff, n);
    scatter_edges<<<512, 256, 0, stream>>>(src, dst, woff, ssrc, E);

    // ---- layer 1 ----
    gemm_dual<64><<<(n + 31) / 32, 256, 0, stream>>>(x, Wl1, bl1, Wr1, br1, xlbuf, xrbuf, n);
    gat_agg<<<(n + 3) / 4, 256, 0, stream>>>(xlbuf, xrbuf, att1, bias1, rowptr, ssrc, hbuf, n);

    // ---- layer 2 ----
    gemm_dual<128><<<(n + 31) / 32, 256, 0, stream>>>(hbuf, Wl2, bl2, Wr2, br2, xlbuf, xrbuf, n);
    gat_agg<<<(n + 3) / 4, 256, 0, stream>>>(xlbuf, xrbuf, att2, bias2, rowptr, ssrc, outp, n);
}

// Round 3
// 313.587 us; speedup vs baseline: 1.9011x; 1.1542x over previous
//
#include <hip/hip_runtime.h>

#define LEAKY 0.2f

typedef __attribute__((ext_vector_type(8))) short  bfrag;   // 8 bf16 = 4 VGPR
typedef __attribute__((ext_vector_type(4))) float  f32x4;

__device__ __forceinline__ unsigned bf16rne(float v) {
    unsigned u = __float_as_uint(v);
    return (u + 0x7FFF + ((u >> 16) & 1)) >> 16;
}
__device__ __forceinline__ float bf16tof(unsigned b) { return __uint_as_float(b << 16); }

// ---------------- counting sort of edges by destination ----------------

__global__ void count_dst(const int* __restrict__ dst, int* __restrict__ cnt, int E) {
    int i = blockIdx.x * blockDim.x + threadIdx.x;
    int stride = gridDim.x * blockDim.x;
    for (int e = i; e < E; e += stride)
        atomicAdd(&cnt[dst[e]], 1);
}

__global__ __launch_bounds__(1024) void scan_chunk(const int* __restrict__ cnt,
                                                   int* __restrict__ incl,
                                                   int* __restrict__ bsum, int n) {
    __shared__ int s[1024];
    int tid = threadIdx.x;
    int i = blockIdx.x * 1024 + tid;
    int v = (i < n) ? cnt[i] : 0;
    s[tid] = v;
    __syncthreads();
    for (int off = 1; off < 1024; off <<= 1) {
        int add = (tid >= off) ? s[tid - off] : 0;
        __syncthreads();
        s[tid] += add;
        __syncthreads();
    }
    incl[i] = s[tid];
    if (tid == 1023) bsum[blockIdx.x] = s[1023];
}

__global__ void scan_bsum(const int* __restrict__ bsum, int* __restrict__ bsumEx, int nb) {
    if (threadIdx.x == 0 && blockIdx.x == 0) {
        int run = 0;
        for (int j = 0; j < nb; ++j) { int t = bsum[j]; bsumEx[j] = run; run += t; }
    }
}

__global__ void finalize_rowptr(const int* __restrict__ cnt, const int* __restrict__ incl,
                                const int* __restrict__ bsumEx, int* __restrict__ rowptr,
                                int* __restrict__ woff, int n) {
    int i = blockIdx.x * blockDim.x + threadIdx.x;
    int stride = gridDim.x * blockDim.x;
    for (int j = i; j < n; j += stride) {
        int rp = incl[j] - cnt[j] + bsumEx[j >> 10];
        rowptr[j] = rp;
        woff[j] = rp;
        if (j == n - 1) rowptr[n] = incl[j] + bsumEx[j >> 10];
    }
}

__global__ void scatter_edges(const int* __restrict__ src, const int* __restrict__ dst,
                              int* __restrict__ woff, int* __restrict__ ssrc, int E) {
    int i = blockIdx.x * blockDim.x + threadIdx.x;
    int stride = gridDim.x * blockDim.x;
    for (int e = i; e < E; e += stride) {
        int d = dst[e];
        int pos = atomicAdd(&woff[d], 1);
        ssrc[pos] = src[e];
    }
}

// ---------------- prep: split x into bf16 hi/lo planes ----------------

__global__ void split_x(const float* __restrict__ x, ushort* __restrict__ xhi,
                        ushort* __restrict__ xlo, int total4) {
    int i = blockIdx.x * blockDim.x + threadIdx.x;
    if (i >= total4) return;
    float4 v = reinterpret_cast<const float4*>(x)[i];
    ushort4 h, l;
    float* vp = &v.x;
    ushort* hp = &h.x;
    ushort* lp = &l.x;
#pragma unroll
    for (int j = 0; j < 4; ++j) {
        unsigned hb = bf16rne(vp[j]);
        hp[j] = (ushort)hb;
        lp[j] = (ushort)bf16rne(vp[j] - bf16tof(hb));
    }
    reinterpret_cast<ushort4*>(xhi)[i] = h;
    reinterpret_cast<ushort4*>(xlo)[i] = l;
}

// ---------------- prep: pack [Wl|Wr] into MFMA B-fragment order ----------------
// b-frag (s = k/32, f = col/16): lane l, elem j holds W[s*32 + (l>>4)*8 + j][f*16 + (l&15)]
// packed linearly: pos = ((s*16 + f)*64 + lane)*8 + j   (ushort)

__global__ void pack_W(const float* __restrict__ Wl, const float* __restrict__ Wr,
                       ushort* __restrict__ Bhi, ushort* __restrict__ Blo, int K) {
    int tid = blockIdx.x * blockDim.x + threadIdx.x;
    if (tid >= K * 256) return;
    int k = tid >> 8;
    int c = tid & 255;
    float w = (c < 128) ? Wl[k * 128 + c] : Wr[k * 128 + (c - 128)];
    int s = k >> 5, kin = k & 31, kgrp = kin >> 3, j = kin & 7;
    int f = c >> 4, cin = c & 15;
    int lane = kgrp * 16 + cin;
    size_t pos = ((size_t)(s * 16 + f) * 64 + lane) * 8 + j;
    unsigned hb = bf16rne(w);
    Bhi[pos] = (ushort)hb;
    Blo[pos] = (ushort)bf16rne(w - bf16tof(hb));
}

// ---------------- MFMA GEMM: [xl|xr] = A @ [Wl|Wr] + [bl|br] ----------------
// A: [n][K] bf16 hi/lo planes. Block = 256 thr = 4 waves; wave w owns rows
// [blk*64 + 16w, +16) x all 256 cols (16 col-frags). No LDS, no barriers:
// A-frags straight from global (each row read once), B-frags from packed
// L2-resident buffer. Split-bf16: acc += alo*bhi + ahi*blo + ahi*bhi.

template<int K>
__global__ __launch_bounds__(256) void gemm_mfma(
    const ushort* __restrict__ Ahi, const ushort* __restrict__ Alo,
    const ushort* __restrict__ Bhi, const ushort* __restrict__ Blo,
    const float* __restrict__ bl, const float* __restrict__ br,
    float* __restrict__ xl, float* __restrict__ xr, int n)
{
    const int w = threadIdx.x >> 6;
    const int lane = threadIdx.x & 63;
    const int r0 = blockIdx.x * 64 + w * 16;
    const int arow_ = r0 + (lane & 15);
    const int arow = (arow_ < n) ? arow_ : 0;     // clamp loads; stores guarded
    const int kg = lane >> 4;                     // 0..3

    f32x4 acc[16];
#pragma unroll
    for (int f = 0; f < 16; ++f) acc[f] = (f32x4){0.f, 0.f, 0.f, 0.f};

#pragma unroll
    for (int s = 0; s < K / 32; ++s) {
        const size_t ao = (size_t)arow * K + s * 32 + kg * 8;
        bfrag ahi = *reinterpret_cast<const bfrag*>(&Ahi[ao]);
        bfrag alo = *reinterpret_cast<const bfrag*>(&Alo[ao]);
#pragma unroll
        for (int f = 0; f < 16; ++f) {
            const size_t bo = ((size_t)(s * 16 + f) * 64 + lane) * 8;
            bfrag bhi = *reinterpret_cast<const bfrag*>(&Bhi[bo]);
            bfrag blo = *reinterpret_cast<const bfrag*>(&Blo[bo]);
            acc[f] = __builtin_amdgcn_mfma_f32_16x16x32_bf16(alo, bhi, acc[f], 0, 0, 0);
            acc[f] = __builtin_amdgcn_mfma_f32_16x16x32_bf16(ahi, blo, acc[f], 0, 0, 0);
            acc[f] = __builtin_amdgcn_mfma_f32_16x16x32_bf16(ahi, bhi, acc[f], 0, 0, 0);
        }
    }

    // D layout: col = f*16 + (lane&15), row = r0 + (lane>>4)*4 + reg
    const int cin = lane & 15;
    const int orow0 = r0 + kg * 4;
#pragma unroll
    for (int f = 0; f < 16; ++f) {
        const int col = f * 16 + cin;           // f<8 -> xl, f>=8 -> xr (wave-uniform)
        const int cc = col & 127;
        const float bv = (f < 8) ? bl[cc] : br[cc];
        float* __restrict__ base = (f < 8) ? xl : xr;
#pragma unroll
        for (int j = 0; j < 4; ++j) {
            const int rr = orow0 + j;
            if (rr < n) base[(size_t)rr * 128 + cc] = acc[f][j] + bv;
        }
    }
}

// ---------------- fused per-destination GATv2 aggregation ----------------
// One node per 64-lane wave; lane owns channels (2l, 2l+1). Edge loop x4
// unrolled for ILP. OUTMODE 0: f32 out. OUTMODE 1: bf16 hi/lo planes (feeds
// the next layer's MFMA GEMM directly).

template<int OUTMODE>
__global__ __launch_bounds__(256) void gat_agg(
    const float* __restrict__ xl, const float* __restrict__ xr,
    const float* __restrict__ att, const float* __restrict__ bias,
    const int* __restrict__ rowptr, const int* __restrict__ ssrc,
    float* __restrict__ out, ushort* __restrict__ ohi, ushort* __restrict__ olo,
    int n)
{
    const int node = blockIdx.x * 4 + (threadIdx.x >> 6);
    if (node >= n) return;
    const int lane = threadIdx.x & 63;

    const float2* __restrict__ xl2 = reinterpret_cast<const float2*>(xl);
    const float2 a2  = *reinterpret_cast<const float2*>(&att[lane * 2]);
    const float2 xrv = *reinterpret_cast<const float2*>(&xr[(size_t)node * 128 + lane * 2]);

    float den = 0.f, acc0 = 0.f, acc1 = 0.f;

#define EDGE(v)                                                       \
    {                                                                 \
        float e0 = (v).x + xrv.x, e1 = (v).y + xrv.y;                 \
        e0 = e0 > 0.f ? e0 : LEAKY * e0;                              \
        e1 = e1 > 0.f ? e1 : LEAKY * e1;                              \
        float p = e0 * a2.x + e1 * a2.y;                              \
        p += __shfl_xor(p, 1);                                        \
        p += __shfl_xor(p, 2);                                        \
        p += __shfl_xor(p, 4);                                        \
        p += __shfl_xor(p, 8);                                        \
        float ex = __expf(p);                                         \
        den  += ex;                                                   \
        acc0 += ex * (v).x;                                           \
        acc1 += ex * (v).y;                                           \
    }

    // self loop
    {
        float2 v = xl2[(size_t)node * 64 + lane];
        EDGE(v);
    }

    int i = rowptr[node];
    const int end = rowptr[node + 1];
    for (; i + 4 <= end; i += 4) {
        int s0 = ssrc[i], s1 = ssrc[i + 1], s2 = ssrc[i + 2], s3 = ssrc[i + 3];
        float2 v0 = xl2[(size_t)s0 * 64 + lane];
        float2 v1 = xl2[(size_t)s1 * 64 + lane];
        float2 v2 = xl2[(size_t)s2 * 64 + lane];
        float2 v3 = xl2[(size_t)s3 * 64 + lane];
        EDGE(v0); EDGE(v1); EDGE(v2); EDGE(v3);
    }
    for (; i < end; ++i) {
        float2 v = xl2[(size_t)ssrc[i] * 64 + lane];
        EDGE(v);
    }
#undef EDGE

    const float rden = 1.f / den;
    float o0 = fmaxf(acc0 * rden + bias[lane * 2],     0.f);
    float o1 = fmaxf(acc1 * rden + bias[lane * 2 + 1], 0.f);

    if (OUTMODE == 0) {
        *reinterpret_cast<float2*>(&out[(size_t)node * 128 + lane * 2]) =
            make_float2(o0, o1);
    } else {
        unsigned h0 = bf16rne(o0), h1 = bf16rne(o1);
        ushort2 hv = make_ushort2((ushort)h0, (ushort)h1);
        ushort2 lv = make_ushort2((ushort)bf16rne(o0 - bf16tof(h0)),
                                  (ushort)bf16rne(o1 - bf16tof(h1)));
        *reinterpret_cast<ushort2*>(&ohi[(size_t)node * 128 + lane * 2]) = hv;
        *reinterpret_cast<ushort2*>(&olo[(size_t)node * 128 + lane * 2]) = lv;
    }
}

// ---------------- launch ----------------

extern "C" void kernel_launch(void* const* d_in, const int* in_sizes, int n_in,
                              void* d_out, int out_size, void* d_ws, size_t ws_size,
                              hipStream_t stream)
{
    const float* x     = (const float*)d_in[0];
    const float* Wl1   = (const float*)d_in[1];
    const float* bl1   = (const float*)d_in[2];
    const float* Wr1   = (const float*)d_in[3];
    const float* br1   = (const float*)d_in[4];
    const float* att1  = (const float*)d_in[5];
    const float* bias1 = (const float*)d_in[6];
    const float* Wl2   = (const float*)d_in[7];
    const float* bl2   = (const float*)d_in[8];
    const float* Wr2   = (const float*)d_in[9];
    const float* br2   = (const float*)d_in[10];
    const float* att2  = (const float*)d_in[11];
    const float* bias2 = (const float*)d_in[12];
    const int*   eidx  = (const int*)d_in[13];

    const int n = in_sizes[0] / 64;
    const int E = in_sizes[13] / 2;
    const int* src = eidx;
    const int* dst = eidx + E;

    char* ws = (char*)d_ws;
    size_t off = 0;
    auto alloc = [&](size_t bytes) -> void* {
        void* p = ws + off;
        off = (off + bytes + 255) & ~(size_t)255;
        return p;
    };
    const int nb = (n + 1023) / 1024;
    int* cnt      = (int*)alloc((size_t)n * 4);
    int* incl     = (int*)alloc((size_t)nb * 1024 * 4);
    int* bsum     = (int*)alloc((size_t)nb * 4);
    int* bsumEx   = (int*)alloc((size_t)nb * 4);
    int* rowptr   = (int*)alloc((size_t)(n + 1) * 4);
    int* woff     = (int*)alloc((size_t)n * 4);
    int* ssrc     = (int*)alloc((size_t)E * 4);
    ushort* B1hi  = (ushort*)alloc((size_t)64  * 256 * 2);
    ushort* B1lo  = (ushort*)alloc((size_t)64  * 256 * 2);
    ushort* B2hi  = (ushort*)alloc((size_t)128 * 256 * 2);
    ushort* B2lo  = (ushort*)alloc((size_t)128 * 256 * 2);
    // X region (25.6MB): xhi1/xlo1 (layer-1 A, n*64 each) live first; after
    // gemm1 consumes them, agg1 overwrites the region with hhi/hlo (n*128 each).
    ushort* xreg  = (ushort*)alloc((size_t)n * 128 * 2 * 2);
    ushort* xhi1  = xreg;
    ushort* xlo1  = xreg + (size_t)n * 64;
    ushort* hhi   = xreg;
    ushort* hlo   = xreg + (size_t)n * 128;
    float* xlbuf  = (float*)alloc((size_t)n * 128 * 4);
    float* xrbuf  = (float*)alloc((size_t)n * 128 * 4);
    float* outp   = (float*)d_out;

    // ---- build CSR by dst (graph fixed: reused by both layers) ----
    hipMemsetAsync(cnt, 0, (size_t)n * 4, stream);
    count_dst<<<512, 256, 0, stream>>>(dst, cnt, E);
    scan_chunk<<<nb, 1024, 0, stream>>>(cnt, incl, bsum, n);
    scan_bsum<<<1, 64, 0, stream>>>(bsum, bsumEx, nb);
    finalize_rowptr<<<(n + 255) / 256, 256, 0, stream>>>(cnt, incl, bsumEx, rowptr, woff, n);
    scatter_edges<<<512, 256, 0, stream>>>(src, dst, woff, ssrc, E);

    // ---- prep: bf16 hi/lo splits ----
    const int total4 = n * 64 / 4;
    split_x<<<(total4 + 255) / 256, 256, 0, stream>>>(x, xhi1, xlo1, total4);
    pack_W<<<(64  * 256 + 255) / 256, 256, 0, stream>>>(Wl1, Wr1, B1hi, B1lo, 64);
    pack_W<<<(128 * 256 + 255) / 256, 256, 0, stream>>>(Wl2, Wr2, B2hi, B2lo, 128);

    const int gblk = (n + 63) / 64;

    // ---- layer 1 ----
    gemm_mfma<64><<<gblk, 256, 0, stream>>>(xhi1, xlo1, B1hi, B1lo, bl1, br1,
                                            xlbuf, xrbuf, n);
    gat_agg<1><<<(n + 3) / 4, 256, 0, stream>>>(xlbuf, xrbuf, att1, bias1, rowptr, ssrc,
                                                nullptr, hhi, hlo, n);

    // ---- layer 2 ----
    gemm_mfma<128><<<gblk, 256, 0, stream>>>(hhi, hlo, B2hi, B2lo, bl2, br2,
                                             xlbuf, xrbuf, n);
    gat_agg<0><<<(n + 3) / 4, 256, 0, stream>>>(xlbuf, xrbuf, att2, bias2, rowptr, ssrc,
                                                outp, nullptr, nullptr, n);
}

// Round 4
// 309.931 us; speedup vs baseline: 1.9235x; 1.0118x over previous
//
#include <hip/hip_runtime.h>

#define LEAKY 0.2f
#define NBSHIFT 8          // 256 nodes per bucket
#define TILE 4096          // edges per multisplit block

typedef __attribute__((ext_vector_type(8))) short  bfrag;   // 8 bf16 = 4 VGPR
typedef __attribute__((ext_vector_type(4))) float  f32x4;

__device__ __forceinline__ unsigned bf16rne(float v) {
    unsigned u = __float_as_uint(v);
    return (u + 0x7FFF + ((u >> 16) & 1)) >> 16;
}
__device__ __forceinline__ float bf16tof(unsigned b) { return __uint_as_float(b << 16); }

// ---------------- CSR build: bucketed multisplit ----------------

__global__ __launch_bounds__(256) void bucket_hist(const int* __restrict__ dst,
                                                   int* __restrict__ bcnt, int E, int nb) {
    __shared__ int h[256];
    h[threadIdx.x] = 0;
    __syncthreads();
    for (int e = blockIdx.x * 256 + threadIdx.x; e < E; e += gridDim.x * 256)
        atomicAdd(&h[dst[e] >> NBSHIFT], 1);
    __syncthreads();
    int v = h[threadIdx.x];
    if (threadIdx.x < nb && v) atomicAdd(&bcnt[threadIdx.x], v);
}

__global__ __launch_bounds__(256) void bucket_scan(const int* __restrict__ bcnt,
                                                   int* __restrict__ bbase,
                                                   int* __restrict__ gwoff,
                                                   int* __restrict__ rowptr,
                                                   int E, int nb, int n) {
    __shared__ int s[256];
    const int t = threadIdx.x;
    int v = (t < nb) ? bcnt[t] : 0;
    s[t] = v;
    __syncthreads();
    for (int off = 1; off < 256; off <<= 1) {
        int a = (t >= off) ? s[t - off] : 0;
        __syncthreads();
        s[t] += a;
        __syncthreads();
    }
    int excl = s[t] - v;
    if (t < nb) { bbase[t] = excl; gwoff[t] = excl; }
    if (t == 0) { bbase[nb] = E; rowptr[n] = E; }
}

// Tile-wise multisplit: stage TILE edges in LDS sorted by bucket, reserve
// per-bucket global chunks, flush coalesced runs (avg ~21 edges = 168B).
__global__ __launch_bounds__(256) void multisplit(const int* __restrict__ src,
                                                  const int* __restrict__ dst,
                                                  int* __restrict__ gwoff,
                                                  int2* __restrict__ pairs, int E, int nb) {
    __shared__ int hist[256], lofs[256], gb[256];
    __shared__ int2 st[TILE];
    const int t = threadIdx.x;
    const int tile0 = blockIdx.x * TILE;
    const int tend = min(tile0 + TILE, E);
    hist[t] = 0;
    __syncthreads();
    for (int e = tile0 + t; e < tend; e += 256)
        atomicAdd(&hist[dst[e] >> NBSHIFT], 1);
    __syncthreads();
    int v = hist[t];
    lofs[t] = v;
    __syncthreads();
    for (int off = 1; off < 256; off <<= 1) {
        int a = (t >= off) ? lofs[t - off] : 0;
        __syncthreads();
        lofs[t] += a;
        __syncthreads();
    }
    int excl = lofs[t] - v;
    __syncthreads();
    lofs[t] = excl;
    if (t < nb && v > 0) gb[t] = atomicAdd(&gwoff[t], v);
    hist[t] = 0;
    __syncthreads();
    for (int e = tile0 + t; e < tend; e += 256) {
        int d = dst[e];
        int b = d >> NBSHIFT;
        int r = atomicAdd(&hist[b], 1);
        st[lofs[b] + r] = make_int2(src[e], d);
    }
    __syncthreads();
    const int total = tend - tile0;
    for (int i = t; i < total; i += 256) {
        int2 p = st[i];
        int b = p.y >> NBSHIFT;
        pairs[gb[b] + (i - lofs[b])] = p;
    }
}

// One block per bucket: LDS counting sort over the 256-node range ->
// rowptr + ssrc (writes land in a 16KB single-block region: L2 merges lines).
__global__ __launch_bounds__(256) void bucket_sort(const int2* __restrict__ pairs,
                                                   const int* __restrict__ bbase,
                                                   int* __restrict__ rowptr,
                                                   int* __restrict__ ssrc, int n) {
    __shared__ int hist[256], ofs[256];
    const int b = blockIdx.x, t = threadIdx.x;
    const int base = b << NBSHIFT;
    const int pbeg = bbase[b], pend = bbase[b + 1];
    hist[t] = 0;
    __syncthreads();
    for (int i = pbeg + t; i < pend; i += 256)
        atomicAdd(&hist[pairs[i].y - base], 1);
    __syncthreads();
    int v = hist[t];
    ofs[t] = v;
    __syncthreads();
    for (int off = 1; off < 256; off <<= 1) {
        int a = (t >= off) ? ofs[t - off] : 0;
        __syncthreads();
        ofs[t] += a;
        __syncthreads();
    }
    int excl = ofs[t] - v;
    __syncthreads();
    ofs[t] = excl;
    const int node = base + t;
    if (node < n) rowptr[node] = pbeg + excl;
    __syncthreads();
    for (int i = pbeg + t; i < pend; i += 256) {
        int2 p = pairs[i];
        int pos = atomicAdd(&ofs[p.y - base], 1);
        ssrc[pbeg + pos] = p.x;
    }
}

// ---------------- prep: split x into bf16 hi/lo planes ----------------

__global__ void split_x(const float* __restrict__ x, ushort* __restrict__ xhi,
                        ushort* __restrict__ xlo, int total4) {
    int i = blockIdx.x * blockDim.x + threadIdx.x;
    if (i >= total4) return;
    float4 v = reinterpret_cast<const float4*>(x)[i];
    ushort4 h, l;
    float* vp = &v.x;
    ushort* hp = &h.x;
    ushort* lp = &l.x;
#pragma unroll
    for (int j = 0; j < 4; ++j) {
        unsigned hb = bf16rne(vp[j]);
        hp[j] = (ushort)hb;
        lp[j] = (ushort)bf16rne(vp[j] - bf16tof(hb));
    }
    reinterpret_cast<ushort4*>(xhi)[i] = h;
    reinterpret_cast<ushort4*>(xlo)[i] = l;
}

// ---------------- prep: pack [Wl|Wr] into MFMA B-fragment order ----------------
// b-frag (s = k/32, f = col/16): lane l, elem j holds W[s*32 + (l>>4)*8 + j][f*16 + (l&15)]

__global__ void pack_W(const float* __restrict__ Wl, const float* __restrict__ Wr,
                       ushort* __restrict__ Bhi, ushort* __restrict__ Blo, int K) {
    int tid = blockIdx.x * blockDim.x + threadIdx.x;
    if (tid >= K * 256) return;
    int k = tid >> 8;
    int c = tid & 255;
    float w = (c < 128) ? Wl[k * 128 + c] : Wr[k * 128 + (c - 128)];
    int s = k >> 5, kin = k & 31, kgrp = kin >> 3, j = kin & 7;
    int f = c >> 4, cin = c & 15;
    int lane = kgrp * 16 + cin;
    size_t pos = ((size_t)(s * 16 + f) * 64 + lane) * 8 + j;
    unsigned hb = bf16rne(w);
    Bhi[pos] = (ushort)hb;
    Blo[pos] = (ushort)bf16rne(w - bf16tof(hb));
}

// ---------------- MFMA GEMM: [xl|xr] = A @ [Wl|Wr] + [bl|br] ----------------
// 4 waves/block; wave owns 32 rows x 256 cols (B-fragment loads amortized
// over 2 row-fragments -> half the L2 B-traffic of the 16-row version).
// Split-bf16: acc += alo*bhi + ahi*blo + ahi*bhi.

template<int K>
__global__ __launch_bounds__(256) void gemm_mfma(
    const ushort* __restrict__ Ahi, const ushort* __restrict__ Alo,
    const ushort* __restrict__ Bhi, const ushort* __restrict__ Blo,
    const float* __restrict__ bl, const float* __restrict__ br,
    float* __restrict__ xl, float* __restrict__ xr, int n)
{
    const int w = threadIdx.x >> 6;
    const int lane = threadIdx.x & 63;
    const int r0 = blockIdx.x * 128 + w * 32;
    const int rl = lane & 15;
    const int kg = lane >> 4;
    int ar0 = r0 + rl;      if (ar0 >= n) ar0 = 0;   // clamp loads; stores guarded
    int ar1 = r0 + 16 + rl; if (ar1 >= n) ar1 = 0;

    f32x4 acc0[16], acc1[16];
#pragma unroll
    for (int f = 0; f < 16; ++f) {
        acc0[f] = (f32x4){0.f, 0.f, 0.f, 0.f};
        acc1[f] = (f32x4){0.f, 0.f, 0.f, 0.f};
    }

#pragma unroll
    for (int s = 0; s < K / 32; ++s) {
        const size_t a0 = (size_t)ar0 * K + s * 32 + kg * 8;
        const size_t a1 = (size_t)ar1 * K + s * 32 + kg * 8;
        bfrag a0hi = *reinterpret_cast<const bfrag*>(&Ahi[a0]);
        bfrag a0lo = *reinterpret_cast<const bfrag*>(&Alo[a0]);
        bfrag a1hi = *reinterpret_cast<const bfrag*>(&Ahi[a1]);
        bfrag a1lo = *reinterpret_cast<const bfrag*>(&Alo[a1]);
#pragma unroll
        for (int f = 0; f < 16; ++f) {
            const size_t bo = ((size_t)(s * 16 + f) * 64 + lane) * 8;
            bfrag bhi = *reinterpret_cast<const bfrag*>(&Bhi[bo]);
            bfrag blo = *reinterpret_cast<const bfrag*>(&Blo[bo]);
            acc0[f] = __builtin_amdgcn_mfma_f32_16x16x32_bf16(a0lo, bhi, acc0[f], 0, 0, 0);
            acc0[f] = __builtin_amdgcn_mfma_f32_16x16x32_bf16(a0hi, blo, acc0[f], 0, 0, 0);
            acc0[f] = __builtin_amdgcn_mfma_f32_16x16x32_bf16(a0hi, bhi, acc0[f], 0, 0, 0);
            acc1[f] = __builtin_amdgcn_mfma_f32_16x16x32_bf16(a1lo, bhi, acc1[f], 0, 0, 0);
            acc1[f] = __builtin_amdgcn_mfma_f32_16x16x32_bf16(a1hi, blo, acc1[f], 0, 0, 0);
            acc1[f] = __builtin_amdgcn_mfma_f32_16x16x32_bf16(a1hi, bhi, acc1[f], 0, 0, 0);
        }
    }

    // D layout: col = f*16 + (lane&15), row = rowbase + (lane>>4)*4 + j
    const int cin = lane & 15;
#pragma unroll
    for (int f = 0; f < 16; ++f) {
        const int cc = (f * 16 + cin) & 127;
        const float bv = (f < 8) ? bl[cc] : br[cc];
        float* __restrict__ base_ = (f < 8) ? xl : xr;
#pragma unroll
        for (int j = 0; j < 4; ++j) {
            int rr = r0 + kg * 4 + j;
            if (rr < n) base_[(size_t)rr * 128 + cc] = acc0[f][j] + bv;
            rr += 16;
            if (rr < n) base_[(size_t)rr * 128 + cc] = acc1[f][j] + bv;
        }
    }
}

// ---------------- fused per-destination GATv2 aggregation ----------------
// One node per 64-lane wave; lane owns channels (2l, 2l+1). Edge loop x4
// unrolled for ILP. OUTMODE 0: f32 out. OUTMODE 1: bf16 hi/lo planes.

template<int OUTMODE>
__global__ __launch_bounds__(256) void gat_agg(
    const float* __restrict__ xl, const float* __restrict__ xr,
    const float* __restrict__ att, const float* __restrict__ bias,
    const int* __restrict__ rowptr, const int* __restrict__ ssrc,
    float* __restrict__ out, ushort* __restrict__ ohi, ushort* __restrict__ olo,
    int n)
{
    const int node = blockIdx.x * 4 + (threadIdx.x >> 6);
    if (node >= n) return;
    const int lane = threadIdx.x & 63;

    const float2* __restrict__ xl2 = reinterpret_cast<const float2*>(xl);
    const float2 a2  = *reinterpret_cast<const float2*>(&att[lane * 2]);
    const float2 xrv = *reinterpret_cast<const float2*>(&xr[(size_t)node * 128 + lane * 2]);

    float den = 0.f, acc0 = 0.f, acc1 = 0.f;

#define EDGE(v)                                                       \
    {                                                                 \
        float e0 = (v).x + xrv.x, e1 = (v).y + xrv.y;                 \
        e0 = e0 > 0.f ? e0 : LEAKY * e0;                              \
        e1 = e1 > 0.f ? e1 : LEAKY * e1;                              \
        float p = e0 * a2.x + e1 * a2.y;                              \
        p += __shfl_xor(p, 1);                                        \
        p += __shfl_xor(p, 2);                                        \
        p += __shfl_xor(p, 4);                                        \
        p += __shfl_xor(p, 8);                                        \
        float ex = __expf(p);                                         \
        den  += ex;                                                   \
        acc0 += ex * (v).x;                                           \
        acc1 += ex * (v).y;                                           \
    }

    // self loop
    {
        float2 v = xl2[(size_t)node * 64 + lane];
        EDGE(v);
    }

    int i = rowptr[node];
    const int end = rowptr[node + 1];
    for (; i + 4 <= end; i += 4) {
        int s0 = ssrc[i], s1 = ssrc[i + 1], s2 = ssrc[i + 2], s3 = ssrc[i + 3];
        float2 v0 = xl2[(size_t)s0 * 64 + lane];
        float2 v1 = xl2[(size_t)s1 * 64 + lane];
        float2 v2 = xl2[(size_t)s2 * 64 + lane];
        float2 v3 = xl2[(size_t)s3 * 64 + lane];
        EDGE(v0); EDGE(v1); EDGE(v2); EDGE(v3);
    }
    for (; i < end; ++i) {
        float2 v = xl2[(size_t)ssrc[i] * 64 + lane];
        EDGE(v);
    }
#undef EDGE

    const float rden = 1.f / den;
    float o0 = fmaxf(acc0 * rden + bias[lane * 2],     0.f);
    float o1 = fmaxf(acc1 * rden + bias[lane * 2 + 1], 0.f);

    if (OUTMODE == 0) {
        *reinterpret_cast<float2*>(&out[(size_t)node * 128 + lane * 2]) =
            make_float2(o0, o1);
    } else {
        unsigned h0 = bf16rne(o0), h1 = bf16rne(o1);
        ushort2 hv = make_ushort2((ushort)h0, (ushort)h1);
        ushort2 lv = make_ushort2((ushort)bf16rne(o0 - bf16tof(h0)),
                                  (ushort)bf16rne(o1 - bf16tof(h1)));
        *reinterpret_cast<ushort2*>(&ohi[(size_t)node * 128 + lane * 2]) = hv;
        *reinterpret_cast<ushort2*>(&olo[(size_t)node * 128 + lane * 2]) = lv;
    }
}

// ---------------- launch ----------------

extern "C" void kernel_launch(void* const* d_in, const int* in_sizes, int n_in,
                              void* d_out, int out_size, void* d_ws, size_t ws_size,
                              hipStream_t stream)
{
    const float* x     = (const float*)d_in[0];
    const float* Wl1   = (const float*)d_in[1];
    const float* bl1   = (const float*)d_in[2];
    const float* Wr1   = (const float*)d_in[3];
    const float* br1   = (const float*)d_in[4];
    const float* att1  = (const float*)d_in[5];
    const float* bias1 = (const float*)d_in[6];
    const float* Wl2   = (const float*)d_in[7];
    const float* bl2   = (const float*)d_in[8];
    const float* Wr2   = (const float*)d_in[9];
    const float* br2   = (const float*)d_in[10];
    const float* att2  = (const float*)d_in[11];
    const float* bias2 = (const float*)d_in[12];
    const int*   eidx  = (const int*)d_in[13];

    const int n = in_sizes[0] / 64;
    const int E = in_sizes[13] / 2;
    const int* src = eidx;
    const int* dst = eidx + E;
    const int nb = (n + 255) >> 8;        // 196 buckets

    char* ws = (char*)d_ws;
    size_t off = 0;
    auto alloc = [&](size_t bytes) -> void* {
        void* p = ws + off;
        off = (off + bytes + 255) & ~(size_t)255;
        return p;
    };
    int* rowptr   = (int*)alloc((size_t)(n + 1) * 4);
    int* ssrc     = (int*)alloc((size_t)E * 4);
    int* bcnt     = (int*)alloc((size_t)nb * 4);
    int* bbase    = (int*)alloc((size_t)(nb + 1) * 4);
    int* gwoff    = (int*)alloc((size_t)nb * 4);
    ushort* B1hi  = (ushort*)alloc((size_t)64  * 256 * 2);
    ushort* B1lo  = (ushort*)alloc((size_t)64  * 256 * 2);
    ushort* B2hi  = (ushort*)alloc((size_t)128 * 256 * 2);
    ushort* B2lo  = (ushort*)alloc((size_t)128 * 256 * 2);
    // X region: xhi1/xlo1 (layer-1 A) live first; after gemm1 consumes them,
    // agg1 overwrites the region with hhi/hlo.
    ushort* xreg  = (ushort*)alloc((size_t)n * 128 * 2 * 2);
    ushort* xhi1  = xreg;
    ushort* xlo1  = xreg + (size_t)n * 64;
    ushort* hhi   = xreg;
    ushort* hlo   = xreg + (size_t)n * 128;
    float* xlbuf  = (float*)alloc((size_t)n * 128 * 4);
    float* xrbuf  = (float*)alloc((size_t)n * 128 * 4);
    // pairs (E * 8B = 6.4MB) aliases xlbuf (25.6MB): consumed by bucket_sort
    // strictly before gemm1 writes xlbuf.
    int2* pairs   = (int2*)xlbuf;
    float* outp   = (float*)d_out;

    // ---- CSR build: bucketed multisplit ----
    hipMemsetAsync(bcnt, 0, (size_t)nb * 4, stream);
    bucket_hist<<<128, 256, 0, stream>>>(dst, bcnt, E, nb);
    bucket_scan<<<1, 256, 0, stream>>>(bcnt, bbase, gwoff, rowptr, E, nb, n);
    multisplit<<<(E + TILE - 1) / TILE, 256, 0, stream>>>(src, dst, gwoff, pairs, E, nb);
    bucket_sort<<<nb, 256, 0, stream>>>(pairs, bbase, rowptr, ssrc, n);

    // ---- prep: bf16 hi/lo splits ----
    const int total4 = n * 64 / 4;
    split_x<<<(total4 + 255) / 256, 256, 0, stream>>>(x, xhi1, xlo1, total4);
    pack_W<<<(64  * 256 + 255) / 256, 256, 0, stream>>>(Wl1, Wr1, B1hi, B1lo, 64);
    pack_W<<<(128 * 256 + 255) / 256, 256, 0, stream>>>(Wl2, Wr2, B2hi, B2lo, 128);

    const int gblk = (n + 127) / 128;

    // ---- layer 1 ----
    gemm_mfma<64><<<gblk, 256, 0, stream>>>(xhi1, xlo1, B1hi, B1lo, bl1, br1,
                                            xlbuf, xrbuf, n);
    gat_agg<1><<<(n + 3) / 4, 256, 0, stream>>>(xlbuf, xrbuf, att1, bias1, rowptr, ssrc,
                                                nullptr, hhi, hlo, n);

    // ---- layer 2 ----
    gemm_mfma<128><<<gblk, 256, 0, stream>>>(hhi, hlo, B2hi, B2lo, bl2, br2,
                                             xlbuf, xrbuf, n);
    gat_agg<0><<<(n + 3) / 4, 256, 0, stream>>>(xlbuf, xrbuf, att2, bias2, rowptr, ssrc,
                                                outp, nullptr, nullptr, n);
}

// Round 5
// 242.125 us; speedup vs baseline: 2.4622x; 1.2800x over previous
//
#include <hip/hip_runtime.h>

#define LEAKY 0.2f
#define NBSHIFT 8          // 256 nodes per bucket
#define TILE 4096          // edges per multisplit block

typedef __attribute__((ext_vector_type(8))) short  bfrag;   // 8 bf16 = 4 VGPR
typedef __attribute__((ext_vector_type(4))) float  f32x4;

__device__ __forceinline__ unsigned bf16rne(float v) {
    unsigned u = __float_as_uint(v);
    return (u + 0x7FFF + ((u >> 16) & 1)) >> 16;
}
__device__ __forceinline__ float bf16tof(unsigned b) { return __uint_as_float(b << 16); }

// ---------------- CSR build: bucketed multisplit ----------------

__global__ __launch_bounds__(256) void bucket_hist(const int* __restrict__ dst,
                                                   int* __restrict__ bcnt, int E, int nb) {
    __shared__ int h[256];
    h[threadIdx.x] = 0;
    __syncthreads();
    for (int e = blockIdx.x * 256 + threadIdx.x; e < E; e += gridDim.x * 256)
        atomicAdd(&h[dst[e] >> NBSHIFT], 1);
    __syncthreads();
    int v = h[threadIdx.x];
    if (threadIdx.x < nb && v) atomicAdd(&bcnt[threadIdx.x], v);
}

__global__ __launch_bounds__(256) void bucket_scan(const int* __restrict__ bcnt,
                                                   int* __restrict__ bbase,
                                                   int* __restrict__ gwoff,
                                                   int* __restrict__ rowptr,
                                                   int E, int nb, int n) {
    __shared__ int s[256];
    const int t = threadIdx.x;
    int v = (t < nb) ? bcnt[t] : 0;
    s[t] = v;
    __syncthreads();
    for (int off = 1; off < 256; off <<= 1) {
        int a = (t >= off) ? s[t - off] : 0;
        __syncthreads();
        s[t] += a;
        __syncthreads();
    }
    int excl = s[t] - v;
    if (t < nb) { bbase[t] = excl; gwoff[t] = excl; }
    if (t == 0) { bbase[nb] = E; rowptr[n] = E; }
}

// Tile-wise multisplit: stage TILE edges in LDS sorted by bucket, reserve
// per-bucket global chunks, flush coalesced runs (avg ~21 edges = 168B).
__global__ __launch_bounds__(256) void multisplit(const int* __restrict__ src,
                                                  const int* __restrict__ dst,
                                                  int* __restrict__ gwoff,
                                                  int2* __restrict__ pairs, int E, int nb) {
    __shared__ int hist[256], lofs[256], gb[256];
    __shared__ int2 st[TILE];
    const int t = threadIdx.x;
    const int tile0 = blockIdx.x * TILE;
    const int tend = min(tile0 + TILE, E);
    hist[t] = 0;
    __syncthreads();
    for (int e = tile0 + t; e < tend; e += 256)
        atomicAdd(&hist[dst[e] >> NBSHIFT], 1);
    __syncthreads();
    int v = hist[t];
    lofs[t] = v;
    __syncthreads();
    for (int off = 1; off < 256; off <<= 1) {
        int a = (t >= off) ? lofs[t - off] : 0;
        __syncthreads();
        lofs[t] += a;
        __syncthreads();
    }
    int excl = lofs[t] - v;
    __syncthreads();
    lofs[t] = excl;
    if (t < nb && v > 0) gb[t] = atomicAdd(&gwoff[t], v);
    hist[t] = 0;
    __syncthreads();
    for (int e = tile0 + t; e < tend; e += 256) {
        int d = dst[e];
        int b = d >> NBSHIFT;
        int r = atomicAdd(&hist[b], 1);
        st[lofs[b] + r] = make_int2(src[e], d);
    }
    __syncthreads();
    const int total = tend - tile0;
    for (int i = t; i < total; i += 256) {
        int2 p = st[i];
        int b = p.y >> NBSHIFT;
        pairs[gb[b] + (i - lofs[b])] = p;
    }
}

// One block per bucket: LDS counting sort over the 256-node range ->
// rowptr + ssrc (writes land in a 16KB single-block region: L2 merges lines).
__global__ __launch_bounds__(256) void bucket_sort(const int2* __restrict__ pairs,
                                                   const int* __restrict__ bbase,
                                                   int* __restrict__ rowptr,
                                                   int* __restrict__ ssrc, int n) {
    __shared__ int hist[256], ofs[256];
    const int b = blockIdx.x, t = threadIdx.x;
    const int base = b << NBSHIFT;
    const int pbeg = bbase[b], pend = bbase[b + 1];
    hist[t] = 0;
    __syncthreads();
    for (int i = pbeg + t; i < pend; i += 256)
        atomicAdd(&hist[pairs[i].y - base], 1);
    __syncthreads();
    int v = hist[t];
    ofs[t] = v;
    __syncthreads();
    for (int off = 1; off < 256; off <<= 1) {
        int a = (t >= off) ? ofs[t - off] : 0;
        __syncthreads();
        ofs[t] += a;
        __syncthreads();
    }
    int excl = ofs[t] - v;
    __syncthreads();
    ofs[t] = excl;
    const int node = base + t;
    if (node < n) rowptr[node] = pbeg + excl;
    __syncthreads();
    for (int i = pbeg + t; i < pend; i += 256) {
        int2 p = pairs[i];
        int pos = atomicAdd(&ofs[p.y - base], 1);
        ssrc[pbeg + pos] = p.x;
    }
}

// ---------------- prep: split x into bf16 hi/lo planes ----------------

__global__ void split_x(const float* __restrict__ x, ushort* __restrict__ xhi,
                        ushort* __restrict__ xlo, int total4) {
    int i = blockIdx.x * blockDim.x + threadIdx.x;
    if (i >= total4) return;
    float4 v = reinterpret_cast<const float4*>(x)[i];
    ushort4 h, l;
    float* vp = &v.x;
    ushort* hp = &h.x;
    ushort* lp = &l.x;
#pragma unroll
    for (int j = 0; j < 4; ++j) {
        unsigned hb = bf16rne(vp[j]);
        hp[j] = (ushort)hb;
        lp[j] = (ushort)bf16rne(vp[j] - bf16tof(hb));
    }
    reinterpret_cast<ushort4*>(xhi)[i] = h;
    reinterpret_cast<ushort4*>(xlo)[i] = l;
}

// ---------------- prep: pack [Wl|Wr] into MFMA B-fragment order ----------------
// b-frag (s = k/32, f = col/16): lane l, elem j holds W[s*32 + (l>>4)*8 + j][f*16 + (l&15)]
// packed linearly: pos = ((s*16 + f)*64 + lane)*8 + j   (ushort)

__global__ void pack_W(const float* __restrict__ Wl, const float* __restrict__ Wr,
                       ushort* __restrict__ Bhi, ushort* __restrict__ Blo, int K) {
    int tid = blockIdx.x * blockDim.x + threadIdx.x;
    if (tid >= K * 256) return;
    int k = tid >> 8;
    int c = tid & 255;
    float w = (c < 128) ? Wl[k * 128 + c] : Wr[k * 128 + (c - 128)];
    int s = k >> 5, kin = k & 31, kgrp = kin >> 3, j = kin & 7;
    int f = c >> 4, cin = c & 15;
    int lane = kgrp * 16 + cin;
    size_t pos = ((size_t)(s * 16 + f) * 64 + lane) * 8 + j;
    unsigned hb = bf16rne(w);
    Bhi[pos] = (ushort)hb;
    Blo[pos] = (ushort)bf16rne(w - bf16tof(hb));
}

// ---------------- MFMA GEMM: [xl|xr] = A @ [Wl|Wr] + [bl|br] ----------------
// grid = (row-tiles, 2 N-halves). Block = 4 waves, tile 64 rows x 128 cols.
// B staged in LDS (2 K-steps x 8 col-frags x hi/lo = 32KB -> 4 blocks/CU),
// read back as ds_read_b128 (low latency vs L2 round-trips — round-4's
// 8%-occupancy latency stall). Split-bf16: acc += alo*bhi + ahi*blo + ahi*bhi.

template<int K>
__global__ __launch_bounds__(256) void gemm_mfma(
    const ushort* __restrict__ Ahi, const ushort* __restrict__ Alo,
    const ushort* __restrict__ Bhi, const ushort* __restrict__ Blo,
    const float* __restrict__ bl, const float* __restrict__ br,
    float* __restrict__ xl, float* __restrict__ xr, int n)
{
    __shared__ ushort BshH[2 * 8 * 64 * 8];   // [ss][fl][lane][j] 16KB
    __shared__ ushort BshL[2 * 8 * 64 * 8];   // 16KB
    const int t = threadIdx.x;
    const int w = t >> 6;
    const int lane = t & 63;
    const int half = blockIdx.y;              // 0 -> xl cols, 1 -> xr cols
    const int r0 = blockIdx.x * 64 + w * 16;
    const int rl = lane & 15;
    const int kg = lane >> 4;
    int arow = r0 + rl; if (arow >= n) arow = 0;   // clamp loads; stores guarded

    const float4* __restrict__ gH = reinterpret_cast<const float4*>(Bhi);
    const float4* __restrict__ gL = reinterpret_cast<const float4*>(Blo);
    float4* __restrict__ sH = reinterpret_cast<float4*>(BshH);
    float4* __restrict__ sL = reinterpret_cast<float4*>(BshL);

    f32x4 acc[8];
#pragma unroll
    for (int f = 0; f < 8; ++f) acc[f] = (f32x4){0.f, 0.f, 0.f, 0.f};

#pragma unroll
    for (int sg = 0; sg < K / 64; ++sg) {
        if (sg) __syncthreads();
        // stage s = 2sg, 2sg+1 for this block's 8 col-frags
#pragma unroll
        for (int i = t; i < 1024; i += 256) {
            int ss = i >> 9, fl = (i >> 6) & 7, ln = i & 63;
            int gidx = ((2 * sg + ss) * 16 + half * 8 + fl) * 64 + ln;
            sH[i] = gH[gidx];
            sL[i] = gL[gidx];
        }
        __syncthreads();

#pragma unroll
        for (int ss = 0; ss < 2; ++ss) {
            const int s = 2 * sg + ss;
            const size_t ao = (size_t)arow * K + s * 32 + kg * 8;
            bfrag ahi = *reinterpret_cast<const bfrag*>(&Ahi[ao]);
            bfrag alo = *reinterpret_cast<const bfrag*>(&Alo[ao]);
#pragma unroll
            for (int fl = 0; fl < 8; ++fl) {
                const int lofs = ((ss * 8 + fl) * 64 + lane) * 8;
                bfrag bhi = *reinterpret_cast<const bfrag*>(&BshH[lofs]);
                bfrag blo = *reinterpret_cast<const bfrag*>(&BshL[lofs]);
                acc[fl] = __builtin_amdgcn_mfma_f32_16x16x32_bf16(alo, bhi, acc[fl], 0, 0, 0);
                acc[fl] = __builtin_amdgcn_mfma_f32_16x16x32_bf16(ahi, blo, acc[fl], 0, 0, 0);
                acc[fl] = __builtin_amdgcn_mfma_f32_16x16x32_bf16(ahi, bhi, acc[fl], 0, 0, 0);
            }
        }
    }

    // D layout: col = fl*16 + (lane&15), row = r0 + (lane>>4)*4 + j
    const int cin = lane & 15;
    const float* __restrict__ bias_ = half ? br : bl;
    float* __restrict__ outp = half ? xr : xl;
#pragma unroll
    for (int fl = 0; fl < 8; ++fl) {
        const int cc = fl * 16 + cin;
        const float bv = bias_[cc];
#pragma unroll
        for (int j = 0; j < 4; ++j) {
            const int rr = r0 + kg * 4 + j;
            if (rr < n) outp[(size_t)rr * 128 + cc] = acc[fl][j] + bv;
        }
    }
}

// ---------------- fused per-destination GATv2 aggregation ----------------
// One node per 64-lane wave; lane owns channels (2l, 2l+1). Edge loop x8
// unrolled for MLP. OUTMODE 0: f32 out. OUTMODE 1: bf16 hi/lo planes.

template<int OUTMODE>
__global__ __launch_bounds__(256) void gat_agg(
    const float* __restrict__ xl, const float* __restrict__ xr,
    const float* __restrict__ att, const float* __restrict__ bias,
    const int* __restrict__ rowptr, const int* __restrict__ ssrc,
    float* __restrict__ out, ushort* __restrict__ ohi, ushort* __restrict__ olo,
    int n)
{
    const int node = blockIdx.x * 4 + (threadIdx.x >> 6);
    if (node >= n) return;
    const int lane = threadIdx.x & 63;

    const float2* __restrict__ xl2 = reinterpret_cast<const float2*>(xl);
    const float2 a2  = *reinterpret_cast<const float2*>(&att[lane * 2]);
    const float2 xrv = *reinterpret_cast<const float2*>(&xr[(size_t)node * 128 + lane * 2]);

    float den = 0.f, acc0 = 0.f, acc1 = 0.f;

#define EDGE(v)                                                       \
    {                                                                 \
        float e0 = (v).x + xrv.x, e1 = (v).y + xrv.y;                 \
        e0 = e0 > 0.f ? e0 : LEAKY * e0;                              \
        e1 = e1 > 0.f ? e1 : LEAKY * e1;                              \
        float p = e0 * a2.x + e1 * a2.y;                              \
        p += __shfl_xor(p, 1);                                        \
        p += __shfl_xor(p, 2);                                        \
        p += __shfl_xor(p, 4);                                        \
        p += __shfl_xor(p, 8);                                        \
        float ex = __expf(p);                                         \
        den  += ex;                                                   \
        acc0 += ex * (v).x;                                           \
        acc1 += ex * (v).y;                                           \
    }

    // self loop
    {
        float2 v = xl2[(size_t)node * 64 + lane];
        EDGE(v);
    }

    int i = rowptr[node];
    const int end = rowptr[node + 1];
    for (; i + 8 <= end; i += 8) {
        int s0 = ssrc[i],     s1 = ssrc[i + 1], s2 = ssrc[i + 2], s3 = ssrc[i + 3];
        int s4 = ssrc[i + 4], s5 = ssrc[i + 5], s6 = ssrc[i + 6], s7 = ssrc[i + 7];
        float2 v0 = xl2[(size_t)s0 * 64 + lane];
        float2 v1 = xl2[(size_t)s1 * 64 + lane];
        float2 v2 = xl2[(size_t)s2 * 64 + lane];
        float2 v3 = xl2[(size_t)s3 * 64 + lane];
        float2 v4 = xl2[(size_t)s4 * 64 + lane];
        float2 v5 = xl2[(size_t)s5 * 64 + lane];
        float2 v6 = xl2[(size_t)s6 * 64 + lane];
        float2 v7 = xl2[(size_t)s7 * 64 + lane];
        EDGE(v0); EDGE(v1); EDGE(v2); EDGE(v3);
        EDGE(v4); EDGE(v5); EDGE(v6); EDGE(v7);
    }
    for (; i < end; ++i) {
        float2 v = xl2[(size_t)ssrc[i] * 64 + lane];
        EDGE(v);
    }
#undef EDGE

    const float rden = 1.f / den;
    float o0 = fmaxf(acc0 * rden + bias[lane * 2],     0.f);
    float o1 = fmaxf(acc1 * rden + bias[lane * 2 + 1], 0.f);

    if (OUTMODE == 0) {
        *reinterpret_cast<float2*>(&out[(size_t)node * 128 + lane * 2]) =
            make_float2(o0, o1);
    } else {
        unsigned h0 = bf16rne(o0), h1 = bf16rne(o1);
        ushort2 hv = make_ushort2((ushort)h0, (ushort)h1);
        ushort2 lv = make_ushort2((ushort)bf16rne(o0 - bf16tof(h0)),
                                  (ushort)bf16rne(o1 - bf16tof(h1)));
        *reinterpret_cast<ushort2*>(&ohi[(size_t)node * 128 + lane * 2]) = hv;
        *reinterpret_cast<ushort2*>(&olo[(size_t)node * 128 + lane * 2]) = lv;
    }
}

// ---------------- launch ----------------

extern "C" void kernel_launch(void* const* d_in, const int* in_sizes, int n_in,
                              void* d_out, int out_size, void* d_ws, size_t ws_size,
                              hipStream_t stream)
{
    const float* x     = (const float*)d_in[0];
    const float* Wl1   = (const float*)d_in[1];
    const float* bl1   = (const float*)d_in[2];
    const float* Wr1   = (const float*)d_in[3];
    const float* br1   = (const float*)d_in[4];
    const float* att1  = (const float*)d_in[5];
    const float* bias1 = (const float*)d_in[6];
    const float* Wl2   = (const float*)d_in[7];
    const float* bl2   = (const float*)d_in[8];
    const float* Wr2   = (const float*)d_in[9];
    const float* br2   = (const float*)d_in[10];
    const float* att2  = (const float*)d_in[11];
    const float* bias2 = (const float*)d_in[12];
    const int*   eidx  = (const int*)d_in[13];

    const int n = in_sizes[0] / 64;
    const int E = in_sizes[13] / 2;
    const int* src = eidx;
    const int* dst = eidx + E;
    const int nb = (n + 255) >> 8;        // 196 buckets

    char* ws = (char*)d_ws;
    size_t off = 0;
    auto alloc = [&](size_t bytes) -> void* {
        void* p = ws + off;
        off = (off + bytes + 255) & ~(size_t)255;
        return p;
    };
    int* rowptr   = (int*)alloc((size_t)(n + 1) * 4);
    int* ssrc     = (int*)alloc((size_t)E * 4);
    int* bcnt     = (int*)alloc((size_t)nb * 4);
    int* bbase    = (int*)alloc((size_t)(nb + 1) * 4);
    int* gwoff    = (int*)alloc((size_t)nb * 4);
    ushort* B1hi  = (ushort*)alloc((size_t)64  * 256 * 2);
    ushort* B1lo  = (ushort*)alloc((size_t)64  * 256 * 2);
    ushort* B2hi  = (ushort*)alloc((size_t)128 * 256 * 2);
    ushort* B2lo  = (ushort*)alloc((size_t)128 * 256 * 2);
    // X region: xhi1/xlo1 (layer-1 A) live first; after gemm1 consumes them,
    // agg1 overwrites the region with hhi/hlo.
    ushort* xreg  = (ushort*)alloc((size_t)n * 128 * 2 * 2);
    ushort* xhi1  = xreg;
    ushort* xlo1  = xreg + (size_t)n * 64;
    ushort* hhi   = xreg;
    ushort* hlo   = xreg + (size_t)n * 128;
    float* xlbuf  = (float*)alloc((size_t)n * 128 * 4);
    float* xrbuf  = (float*)alloc((size_t)n * 128 * 4);
    // pairs (E * 8B = 6.4MB) aliases xlbuf (25.6MB): consumed by bucket_sort
    // strictly before gemm1 writes xlbuf.
    int2* pairs   = (int2*)xlbuf;
    float* outp   = (float*)d_out;

    // ---- CSR build: bucketed multisplit ----
    hipMemsetAsync(bcnt, 0, (size_t)nb * 4, stream);
    bucket_hist<<<128, 256, 0, stream>>>(dst, bcnt, E, nb);
    bucket_scan<<<1, 256, 0, stream>>>(bcnt, bbase, gwoff, rowptr, E, nb, n);
    multisplit<<<(E + TILE - 1) / TILE, 256, 0, stream>>>(src, dst, gwoff, pairs, E, nb);
    bucket_sort<<<nb, 256, 0, stream>>>(pairs, bbase, rowptr, ssrc, n);

    // ---- prep: bf16 hi/lo splits ----
    const int total4 = n * 64 / 4;
    split_x<<<(total4 + 255) / 256, 256, 0, stream>>>(x, xhi1, xlo1, total4);
    pack_W<<<(64  * 256 + 255) / 256, 256, 0, stream>>>(Wl1, Wr1, B1hi, B1lo, 64);
    pack_W<<<(128 * 256 + 255) / 256, 256, 0, stream>>>(Wl2, Wr2, B2hi, B2lo, 128);

    const dim3 ggrid((n + 63) / 64, 2);

    // ---- layer 1 ----
    gemm_mfma<64><<<ggrid, 256, 0, stream>>>(xhi1, xlo1, B1hi, B1lo, bl1, br1,
                                             xlbuf, xrbuf, n);
    gat_agg<1><<<(n + 3) / 4, 256, 0, stream>>>(xlbuf, xrbuf, att1, bias1, rowptr, ssrc,
                                                nullptr, hhi, hlo, n);

    // ---- layer 2 ----
    gemm_mfma<128><<<ggrid, 256, 0, stream>>>(hhi, hlo, B2hi, B2lo, bl2, br2,
                                              xlbuf, xrbuf, n);
    gat_agg<0><<<(n + 3) / 4, 256, 0, stream>>>(xlbuf, xrbuf, att2, bias2, rowptr, ssrc,
                                                outp, nullptr, nullptr, n);
}

// Round 6
// 209.975 us; speedup vs baseline: 2.8392x; 1.1531x over previous
//
#include <hip/hip_runtime.h>

#define LEAKY 0.2f
#define NBSHIFT 8          // 256 nodes per bucket
#define TILE 4096          // edges per multisplit block

typedef __attribute__((ext_vector_type(8))) short  bfrag;   // 8 bf16 = 4 VGPR
typedef __attribute__((ext_vector_type(4))) float  f32x4;

__device__ __forceinline__ unsigned bf16rne(float v) {
    unsigned u = __float_as_uint(v);
    return (u + 0x7FFF + ((u >> 16) & 1)) >> 16;
}
__device__ __forceinline__ float bf16tof(unsigned b) { return __uint_as_float(b << 16); }

// 16-lane sum via pure-VALU DPP (no ds_swizzle/lgkm waits):
// quad_perm xor1, xor2, then row_ror:4, row_ror:8 (rotations map quads
// uniformly, so the composition yields the full 16-lane sum in every lane).
#define DPPADD(p, ctrl)                                                       \
    p += __int_as_float(__builtin_amdgcn_mov_dpp(__float_as_int(p), ctrl,     \
                                                 0xF, 0xF, true))
__device__ __forceinline__ float rowsum16(float p) {
    DPPADD(p, 0xB1);   // quad_perm [1,0,3,2]  = xor 1
    DPPADD(p, 0x4E);   // quad_perm [2,3,0,1]  = xor 2
    DPPADD(p, 0x124);  // row_ror:4
    DPPADD(p, 0x128);  // row_ror:8
    return p;
}

// ---------------- CSR build: bucketed multisplit ----------------

__global__ __launch_bounds__(256) void bucket_hist(const int* __restrict__ dst,
                                                   int* __restrict__ bcnt, int E, int nb) {
    __shared__ int h[256];
    h[threadIdx.x] = 0;
    __syncthreads();
    for (int e = blockIdx.x * 256 + threadIdx.x; e < E; e += gridDim.x * 256)
        atomicAdd(&h[dst[e] >> NBSHIFT], 1);
    __syncthreads();
    int v = h[threadIdx.x];
    if (threadIdx.x < nb && v) atomicAdd(&bcnt[threadIdx.x], v);
}

__global__ __launch_bounds__(256) void bucket_scan(const int* __restrict__ bcnt,
                                                   int* __restrict__ bbase,
                                                   int* __restrict__ gwoff,
                                                   int* __restrict__ rowptr,
                                                   int E, int nb, int n) {
    __shared__ int s[256];
    const int t = threadIdx.x;
    int v = (t < nb) ? bcnt[t] : 0;
    s[t] = v;
    __syncthreads();
    for (int off = 1; off < 256; off <<= 1) {
        int a = (t >= off) ? s[t - off] : 0;
        __syncthreads();
        s[t] += a;
        __syncthreads();
    }
    int excl = s[t] - v;
    if (t < nb) { bbase[t] = excl; gwoff[t] = excl; }
    if (t == 0) { bbase[nb] = E; rowptr[n] = E; }
}

// Tile-wise multisplit: stage TILE edges in LDS sorted by bucket, reserve
// per-bucket global chunks, flush coalesced runs (avg ~21 edges = 168B).
__global__ __launch_bounds__(256) void multisplit(const int* __restrict__ src,
                                                  const int* __restrict__ dst,
                                                  int* __restrict__ gwoff,
                                                  int2* __restrict__ pairs, int E, int nb) {
    __shared__ int hist[256], lofs[256], gb[256];
    __shared__ int2 st[TILE];
    const int t = threadIdx.x;
    const int tile0 = blockIdx.x * TILE;
    const int tend = min(tile0 + TILE, E);
    hist[t] = 0;
    __syncthreads();
    for (int e = tile0 + t; e < tend; e += 256)
        atomicAdd(&hist[dst[e] >> NBSHIFT], 1);
    __syncthreads();
    int v = hist[t];
    lofs[t] = v;
    __syncthreads();
    for (int off = 1; off < 256; off <<= 1) {
        int a = (t >= off) ? lofs[t - off] : 0;
        __syncthreads();
        lofs[t] += a;
        __syncthreads();
    }
    int excl = lofs[t] - v;
    __syncthreads();
    lofs[t] = excl;
    if (t < nb && v > 0) gb[t] = atomicAdd(&gwoff[t], v);
    hist[t] = 0;
    __syncthreads();
    for (int e = tile0 + t; e < tend; e += 256) {
        int d = dst[e];
        int b = d >> NBSHIFT;
        int r = atomicAdd(&hist[b], 1);
        st[lofs[b] + r] = make_int2(src[e], d);
    }
    __syncthreads();
    const int total = tend - tile0;
    for (int i = t; i < total; i += 256) {
        int2 p = st[i];
        int b = p.y >> NBSHIFT;
        pairs[gb[b] + (i - lofs[b])] = p;
    }
}

// One block per bucket: LDS counting sort over the 256-node range ->
// rowptr + ssrc (writes land in a 16KB single-block region: L2 merges lines).
__global__ __launch_bounds__(256) void bucket_sort(const int2* __restrict__ pairs,
                                                   const int* __restrict__ bbase,
                                                   int* __restrict__ rowptr,
                                                   int* __restrict__ ssrc, int n) {
    __shared__ int hist[256], ofs[256];
    const int b = blockIdx.x, t = threadIdx.x;
    const int base = b << NBSHIFT;
    const int pbeg = bbase[b], pend = bbase[b + 1];
    hist[t] = 0;
    __syncthreads();
    for (int i = pbeg + t; i < pend; i += 256)
        atomicAdd(&hist[pairs[i].y - base], 1);
    __syncthreads();
    int v = hist[t];
    ofs[t] = v;
    __syncthreads();
    for (int off = 1; off < 256; off <<= 1) {
        int a = (t >= off) ? ofs[t - off] : 0;
        __syncthreads();
        ofs[t] += a;
        __syncthreads();
    }
    int excl = ofs[t] - v;
    __syncthreads();
    ofs[t] = excl;
    const int node = base + t;
    if (node < n) rowptr[node] = pbeg + excl;
    __syncthreads();
    for (int i = pbeg + t; i < pend; i += 256) {
        int2 p = pairs[i];
        int pos = atomicAdd(&ofs[p.y - base], 1);
        ssrc[pbeg + pos] = p.x;
    }
}

// ---------------- prep: split x into bf16 hi/lo planes ----------------

__global__ void split_x(const float* __restrict__ x, ushort* __restrict__ xhi,
                        ushort* __restrict__ xlo, int total4) {
    int i = blockIdx.x * blockDim.x + threadIdx.x;
    if (i >= total4) return;
    float4 v = reinterpret_cast<const float4*>(x)[i];
    ushort4 h, l;
    float* vp = &v.x;
    ushort* hp = &h.x;
    ushort* lp = &l.x;
#pragma unroll
    for (int j = 0; j < 4; ++j) {
        unsigned hb = bf16rne(vp[j]);
        hp[j] = (ushort)hb;
        lp[j] = (ushort)bf16rne(vp[j] - bf16tof(hb));
    }
    reinterpret_cast<ushort4*>(xhi)[i] = h;
    reinterpret_cast<ushort4*>(xlo)[i] = l;
}

// ---------------- prep: pack [Wl|Wr] into MFMA B-fragment order ----------------
// b-frag (s = k/32, f = col/16): lane l, elem j holds W[s*32 + (l>>4)*8 + j][f*16 + (l&15)]
// packed linearly: pos = ((s*16 + f)*64 + lane)*8 + j   (ushort)

__global__ void pack_W(const float* __restrict__ Wl, const float* __restrict__ Wr,
                       ushort* __restrict__ Bhi, ushort* __restrict__ Blo, int K) {
    int tid = blockIdx.x * blockDim.x + threadIdx.x;
    if (tid >= K * 256) return;
    int k = tid >> 8;
    int c = tid & 255;
    float w = (c < 128) ? Wl[k * 128 + c] : Wr[k * 128 + (c - 128)];
    int s = k >> 5, kin = k & 31, kgrp = kin >> 3, j = kin & 7;
    int f = c >> 4, cin = c & 15;
    int lane = kgrp * 16 + cin;
    size_t pos = ((size_t)(s * 16 + f) * 64 + lane) * 8 + j;
    unsigned hb = bf16rne(w);
    Bhi[pos] = (ushort)hb;
    Blo[pos] = (ushort)bf16rne(w - bf16tof(hb));
}

// ---------------- MFMA GEMM: [xl|xr] = A @ [Wl|Wr] + [bl|br] ----------------
// grid = (row-tiles, 2 N-halves). Block = 4 waves, tile 64 rows x 128 cols.
// B staged in LDS (32KB -> 4 blocks/CU), read via ds_read_b128.
// Split-bf16: acc += alo*bhi + ahi*blo + ahi*bhi.
// half 0 writes xl as a SINGLE bf16 plane (gat_agg gathers it: half the
// bytes of f32); half 1 writes xr as f32 (read once, sequential).

template<int K>
__global__ __launch_bounds__(256) void gemm_mfma(
    const ushort* __restrict__ Ahi, const ushort* __restrict__ Alo,
    const ushort* __restrict__ Bhi, const ushort* __restrict__ Blo,
    const float* __restrict__ bl, const float* __restrict__ br,
    ushort* __restrict__ xlb, float* __restrict__ xr, int n)
{
    __shared__ ushort BshH[2 * 8 * 64 * 8];   // [ss][fl][lane][j] 16KB
    __shared__ ushort BshL[2 * 8 * 64 * 8];   // 16KB
    const int t = threadIdx.x;
    const int w = t >> 6;
    const int lane = t & 63;
    const int half = blockIdx.y;              // 0 -> xl cols, 1 -> xr cols
    const int r0 = blockIdx.x * 64 + w * 16;
    const int rl = lane & 15;
    const int kg = lane >> 4;
    int arow = r0 + rl; if (arow >= n) arow = 0;   // clamp loads; stores guarded

    const float4* __restrict__ gH = reinterpret_cast<const float4*>(Bhi);
    const float4* __restrict__ gL = reinterpret_cast<const float4*>(Blo);
    float4* __restrict__ sH = reinterpret_cast<float4*>(BshH);
    float4* __restrict__ sL = reinterpret_cast<float4*>(BshL);

    f32x4 acc[8];
#pragma unroll
    for (int f = 0; f < 8; ++f) acc[f] = (f32x4){0.f, 0.f, 0.f, 0.f};

#pragma unroll
    for (int sg = 0; sg < K / 64; ++sg) {
        if (sg) __syncthreads();
        // stage s = 2sg, 2sg+1 for this block's 8 col-frags
#pragma unroll
        for (int i = t; i < 1024; i += 256) {
            int ss = i >> 9, fl = (i >> 6) & 7, ln = i & 63;
            int gidx = ((2 * sg + ss) * 16 + half * 8 + fl) * 64 + ln;
            sH[i] = gH[gidx];
            sL[i] = gL[gidx];
        }
        __syncthreads();

#pragma unroll
        for (int ss = 0; ss < 2; ++ss) {
            const int s = 2 * sg + ss;
            const size_t ao = (size_t)arow * K + s * 32 + kg * 8;
            bfrag ahi = *reinterpret_cast<const bfrag*>(&Ahi[ao]);
            bfrag alo = *reinterpret_cast<const bfrag*>(&Alo[ao]);
#pragma unroll
            for (int fl = 0; fl < 8; ++fl) {
                const int lofs = ((ss * 8 + fl) * 64 + lane) * 8;
                bfrag bhi = *reinterpret_cast<const bfrag*>(&BshH[lofs]);
                bfrag blo = *reinterpret_cast<const bfrag*>(&BshL[lofs]);
                acc[fl] = __builtin_amdgcn_mfma_f32_16x16x32_bf16(alo, bhi, acc[fl], 0, 0, 0);
                acc[fl] = __builtin_amdgcn_mfma_f32_16x16x32_bf16(ahi, blo, acc[fl], 0, 0, 0);
                acc[fl] = __builtin_amdgcn_mfma_f32_16x16x32_bf16(ahi, bhi, acc[fl], 0, 0, 0);
            }
        }
    }

    // D layout: col = fl*16 + (lane&15), row = r0 + (lane>>4)*4 + j
    const int cin = lane & 15;
    const float* __restrict__ bias_ = half ? br : bl;
#pragma unroll
    for (int fl = 0; fl < 8; ++fl) {
        const int cc = fl * 16 + cin;
        const float bv = bias_[cc];
#pragma unroll
        for (int j = 0; j < 4; ++j) {
            const int rr = r0 + kg * 4 + j;
            if (rr < n) {
                const float v = acc[fl][j] + bv;
                if (half) xr[(size_t)rr * 128 + cc] = v;
                else      xlb[(size_t)rr * 128 + cc] = (ushort)bf16rne(v);
            }
        }
    }
}

// ---------------- fused per-destination GATv2 aggregation ----------------
// One node per 64-lane wave; lane owns channels (2l, 2l+1), gathered as ONE
// uint (2 bf16 = 4B/lane = 256B/wave/edge). Score reduce = pure-VALU DPP.
// Edge loop x8 unrolled. OUTMODE 0: f32 out. OUTMODE 1: bf16 hi/lo planes.

template<int OUTMODE>
__global__ __launch_bounds__(256) void gat_agg(
    const ushort* __restrict__ xlb, const float* __restrict__ xr,
    const float* __restrict__ att, const float* __restrict__ bias,
    const int* __restrict__ rowptr, const int* __restrict__ ssrc,
    float* __restrict__ out, ushort* __restrict__ ohi, ushort* __restrict__ olo,
    int n)
{
    const int node = blockIdx.x * 4 + (threadIdx.x >> 6);
    if (node >= n) return;
    const int lane = threadIdx.x & 63;

    const uint* __restrict__ xlu = reinterpret_cast<const uint*>(xlb);
    const float2 a2  = *reinterpret_cast<const float2*>(&att[lane * 2]);
    const float2 xrv = *reinterpret_cast<const float2*>(&xr[(size_t)node * 128 + lane * 2]);

    float den = 0.f, acc0 = 0.f, acc1 = 0.f;

#define EDGE(u)                                                       \
    {                                                                 \
        const float x0 = __uint_as_float((u) << 16);                  \
        const float x1 = __uint_as_float((u) & 0xFFFF0000u);          \
        float e0 = x0 + xrv.x, e1 = x1 + xrv.y;                       \
        e0 = e0 > 0.f ? e0 : LEAKY * e0;                              \
        e1 = e1 > 0.f ? e1 : LEAKY * e1;                              \
        float p = rowsum16(e0 * a2.x + e1 * a2.y);                    \
        float ex = __expf(p);                                         \
        den  += ex;                                                   \
        acc0 += ex * x0;                                              \
        acc1 += ex * x1;                                              \
    }

    // self loop
    {
        uint u = xlu[(size_t)node * 64 + lane];
        EDGE(u);
    }

    int i = rowptr[node];
    const int end = rowptr[node + 1];
    for (; i + 8 <= end; i += 8) {
        int s0 = ssrc[i],     s1 = ssrc[i + 1], s2 = ssrc[i + 2], s3 = ssrc[i + 3];
        int s4 = ssrc[i + 4], s5 = ssrc[i + 5], s6 = ssrc[i + 6], s7 = ssrc[i + 7];
        uint u0 = xlu[(size_t)s0 * 64 + lane];
        uint u1 = xlu[(size_t)s1 * 64 + lane];
        uint u2 = xlu[(size_t)s2 * 64 + lane];
        uint u3 = xlu[(size_t)s3 * 64 + lane];
        uint u4 = xlu[(size_t)s4 * 64 + lane];
        uint u5 = xlu[(size_t)s5 * 64 + lane];
        uint u6 = xlu[(size_t)s6 * 64 + lane];
        uint u7 = xlu[(size_t)s7 * 64 + lane];
        EDGE(u0); EDGE(u1); EDGE(u2); EDGE(u3);
        EDGE(u4); EDGE(u5); EDGE(u6); EDGE(u7);
    }
    for (; i < end; ++i) {
        uint u = xlu[(size_t)ssrc[i] * 64 + lane];
        EDGE(u);
    }
#undef EDGE

    const float rden = 1.f / den;
    float o0 = fmaxf(acc0 * rden + bias[lane * 2],     0.f);
    float o1 = fmaxf(acc1 * rden + bias[lane * 2 + 1], 0.f);

    if (OUTMODE == 0) {
        *reinterpret_cast<float2*>(&out[(size_t)node * 128 + lane * 2]) =
            make_float2(o0, o1);
    } else {
        unsigned h0 = bf16rne(o0), h1 = bf16rne(o1);
        ushort2 hv = make_ushort2((ushort)h0, (ushort)h1);
        ushort2 lv = make_ushort2((ushort)bf16rne(o0 - bf16tof(h0)),
                                  (ushort)bf16rne(o1 - bf16tof(h1)));
        *reinterpret_cast<ushort2*>(&ohi[(size_t)node * 128 + lane * 2]) = hv;
        *reinterpret_cast<ushort2*>(&olo[(size_t)node * 128 + lane * 2]) = lv;
    }
}

// ---------------- launch ----------------

extern "C" void kernel_launch(void* const* d_in, const int* in_sizes, int n_in,
                              void* d_out, int out_size, void* d_ws, size_t ws_size,
                              hipStream_t stream)
{
    const float* x     = (const float*)d_in[0];
    const float* Wl1   = (const float*)d_in[1];
    const float* bl1   = (const float*)d_in[2];
    const float* Wr1   = (const float*)d_in[3];
    const float* br1   = (const float*)d_in[4];
    const float* att1  = (const float*)d_in[5];
    const float* bias1 = (const float*)d_in[6];
    const float* Wl2   = (const float*)d_in[7];
    const float* bl2   = (const float*)d_in[8];
    const float* Wr2   = (const float*)d_in[9];
    const float* br2   = (const float*)d_in[10];
    const float* att2  = (const float*)d_in[11];
    const float* bias2 = (const float*)d_in[12];
    const int*   eidx  = (const int*)d_in[13];

    const int n = in_sizes[0] / 64;
    const int E = in_sizes[13] / 2;
    const int* src = eidx;
    const int* dst = eidx + E;
    const int nb = (n + 255) >> 8;        // 196 buckets

    char* ws = (char*)d_ws;
    size_t off = 0;
    auto alloc = [&](size_t bytes) -> void* {
        void* p = ws + off;
        off = (off + bytes + 255) & ~(size_t)255;
        return p;
    };
    int* rowptr   = (int*)alloc((size_t)(n + 1) * 4);
    int* ssrc     = (int*)alloc((size_t)E * 4);
    int* bcnt     = (int*)alloc((size_t)nb * 4);
    int* bbase    = (int*)alloc((size_t)(nb + 1) * 4);
    int* gwoff    = (int*)alloc((size_t)nb * 4);
    ushort* B1hi  = (ushort*)alloc((size_t)64  * 256 * 2);
    ushort* B1lo  = (ushort*)alloc((size_t)64  * 256 * 2);
    ushort* B2hi  = (ushort*)alloc((size_t)128 * 256 * 2);
    ushort* B2lo  = (ushort*)alloc((size_t)128 * 256 * 2);
    // X region: xhi1/xlo1 (layer-1 A) live first; after gemm1 consumes them,
    // agg1 overwrites the region with hhi/hlo.
    ushort* xreg  = (ushort*)alloc((size_t)n * 128 * 2 * 2);
    ushort* xhi1  = xreg;
    ushort* xlo1  = xreg + (size_t)n * 64;
    ushort* hhi   = xreg;
    ushort* hlo   = xreg + (size_t)n * 128;
    ushort* xlb   = (ushort*)alloc((size_t)n * 128 * 2);   // bf16 xl plane
    float* xrbuf  = (float*)alloc((size_t)n * 128 * 4);
    // pairs (E * 8B = 6.8MB) aliases xlb (12.8MB): consumed by bucket_sort
    // strictly before gemm1 writes xlb.
    int2* pairs   = (int2*)xlb;
    float* outp   = (float*)d_out;

    // ---- CSR build: bucketed multisplit ----
    hipMemsetAsync(bcnt, 0, (size_t)nb * 4, stream);
    bucket_hist<<<128, 256, 0, stream>>>(dst, bcnt, E, nb);
    bucket_scan<<<1, 256, 0, stream>>>(bcnt, bbase, gwoff, rowptr, E, nb, n);
    multisplit<<<(E + TILE - 1) / TILE, 256, 0, stream>>>(src, dst, gwoff, pairs, E, nb);
    bucket_sort<<<nb, 256, 0, stream>>>(pairs, bbase, rowptr, ssrc, n);

    // ---- prep: bf16 hi/lo splits ----
    const int total4 = n * 64 / 4;
    split_x<<<(total4 + 255) / 256, 256, 0, stream>>>(x, xhi1, xlo1, total4);
    pack_W<<<(64  * 256 + 255) / 256, 256, 0, stream>>>(Wl1, Wr1, B1hi, B1lo, 64);
    pack_W<<<(128 * 256 + 255) / 256, 256, 0, stream>>>(Wl2, Wr2, B2hi, B2lo, 128);

    const dim3 ggrid((n + 63) / 64, 2);

    // ---- layer 1 ----
    gemm_mfma<64><<<ggrid, 256, 0, stream>>>(xhi1, xlo1, B1hi, B1lo, bl1, br1,
                                             xlb, xrbuf, n);
    gat_agg<1><<<(n + 3) / 4, 256, 0, stream>>>(xlb, xrbuf, att1, bias1, rowptr, ssrc,
                                                nullptr, hhi, hlo, n);

    // ---- layer 2 ----
    gemm_mfma<128><<<ggrid, 256, 0, stream>>>(hhi, hlo, B2hi, B2lo, bl2, br2,
                                              xlb, xrbuf, n);
    gat_agg<0><<<(n + 3) / 4, 256, 0, stream>>>(xlb, xrbuf, att2, bias2, rowptr, ssrc,
                                                outp, nullptr, nullptr, n);
}

// Round 7
// 202.638 us; speedup vs baseline: 2.9420x; 1.0362x over previous
//
#include <hip/hip_runtime.h>

#define LEAKY 0.2f
#define NBSHIFT 8          // 256 nodes per bucket
#define TILE 4096          // edges per multisplit block

typedef __attribute__((ext_vector_type(8))) short  bfrag;   // 8 bf16 = 4 VGPR
typedef __attribute__((ext_vector_type(4))) float  f32x4;

__device__ __forceinline__ unsigned bf16rne(float v) {
    unsigned u = __float_as_uint(v);
    return (u + 0x7FFF + ((u >> 16) & 1)) >> 16;
}
__device__ __forceinline__ float bf16tof(unsigned b) { return __uint_as_float(b << 16); }

// pure-VALU DPP lane sums (no ds_swizzle/lgkm waits)
#define DPPADD(p, ctrl)                                                       \
    p += __int_as_float(__builtin_amdgcn_mov_dpp(__float_as_int(p), ctrl,     \
                                                 0xF, 0xF, true))
// sum over each aligned 8-lane group: xor1, xor2, then half-row mirror
// (lane^7 within the 8-group; quad-sums are quad-uniform so this adds the
// other quad's sum -> full 8-lane sum in every lane of the group).
__device__ __forceinline__ float rowsum8(float p) {
    DPPADD(p, 0xB1);   // quad_perm [1,0,3,2] = xor 1
    DPPADD(p, 0x4E);   // quad_perm [2,3,0,1] = xor 2
    DPPADD(p, 0x141);  // row_half_mirror    = xor 7 within 8-lane group
    return p;
}

// ---------------- CSR build: bucketed multisplit ----------------

__global__ __launch_bounds__(256) void bucket_hist(const int* __restrict__ dst,
                                                   int* __restrict__ bcnt, int E, int nb) {
    __shared__ int h[256];
    h[threadIdx.x] = 0;
    __syncthreads();
    for (int e = blockIdx.x * 256 + threadIdx.x; e < E; e += gridDim.x * 256)
        atomicAdd(&h[dst[e] >> NBSHIFT], 1);
    __syncthreads();
    int v = h[threadIdx.x];
    if (threadIdx.x < nb && v) atomicAdd(&bcnt[threadIdx.x], v);
}

__global__ __launch_bounds__(256) void bucket_scan(const int* __restrict__ bcnt,
                                                   int* __restrict__ bbase,
                                                   int* __restrict__ gwoff,
                                                   int* __restrict__ rowptr,
                                                   int E, int nb, int n) {
    __shared__ int s[256];
    const int t = threadIdx.x;
    int v = (t < nb) ? bcnt[t] : 0;
    s[t] = v;
    __syncthreads();
    for (int off = 1; off < 256; off <<= 1) {
        int a = (t >= off) ? s[t - off] : 0;
        __syncthreads();
        s[t] += a;
        __syncthreads();
    }
    int excl = s[t] - v;
    if (t < nb) { bbase[t] = excl; gwoff[t] = excl; }
    if (t == 0) { bbase[nb] = E; rowptr[n] = E; }
}

// Tile-wise multisplit: stage TILE edges in LDS sorted by bucket, reserve
// per-bucket global chunks, flush coalesced runs (avg ~21 edges = 168B).
__global__ __launch_bounds__(256) void multisplit(const int* __restrict__ src,
                                                  const int* __restrict__ dst,
                                                  int* __restrict__ gwoff,
                                                  int2* __restrict__ pairs, int E, int nb) {
    __shared__ int hist[256], lofs[256], gb[256];
    __shared__ int2 st[TILE];
    const int t = threadIdx.x;
    const int tile0 = blockIdx.x * TILE;
    const int tend = min(tile0 + TILE, E);
    hist[t] = 0;
    __syncthreads();
    for (int e = tile0 + t; e < tend; e += 256)
        atomicAdd(&hist[dst[e] >> NBSHIFT], 1);
    __syncthreads();
    int v = hist[t];
    lofs[t] = v;
    __syncthreads();
    for (int off = 1; off < 256; off <<= 1) {
        int a = (t >= off) ? lofs[t - off] : 0;
        __syncthreads();
        lofs[t] += a;
        __syncthreads();
    }
    int excl = lofs[t] - v;
    __syncthreads();
    lofs[t] = excl;
    if (t < nb && v > 0) gb[t] = atomicAdd(&gwoff[t], v);
    hist[t] = 0;
    __syncthreads();
    for (int e = tile0 + t; e < tend; e += 256) {
        int d = dst[e];
        int b = d >> NBSHIFT;
        int r = atomicAdd(&hist[b], 1);
        st[lofs[b] + r] = make_int2(src[e], d);
    }
    __syncthreads();
    const int total = tend - tile0;
    for (int i = t; i < total; i += 256) {
        int2 p = st[i];
        int b = p.y >> NBSHIFT;
        pairs[gb[b] + (i - lofs[b])] = p;
    }
}

// One block per bucket: LDS counting sort over the 256-node range ->
// rowptr + ssrc (writes land in a 16KB single-block region: L2 merges lines).
__global__ __launch_bounds__(256) void bucket_sort(const int2* __restrict__ pairs,
                                                   const int* __restrict__ bbase,
                                                   int* __restrict__ rowptr,
                                                   int* __restrict__ ssrc, int n) {
    __shared__ int hist[256], ofs[256];
    const int b = blockIdx.x, t = threadIdx.x;
    const int base = b << NBSHIFT;
    const int pbeg = bbase[b], pend = bbase[b + 1];
    hist[t] = 0;
    __syncthreads();
    for (int i = pbeg + t; i < pend; i += 256)
        atomicAdd(&hist[pairs[i].y - base], 1);
    __syncthreads();
    int v = hist[t];
    ofs[t] = v;
    __syncthreads();
    for (int off = 1; off < 256; off <<= 1) {
        int a = (t >= off) ? ofs[t - off] : 0;
        __syncthreads();
        ofs[t] += a;
        __syncthreads();
    }
    int excl = ofs[t] - v;
    __syncthreads();
    ofs[t] = excl;
    const int node = base + t;
    if (node < n) rowptr[node] = pbeg + excl;
    __syncthreads();
    for (int i = pbeg + t; i < pend; i += 256) {
        int2 p = pairs[i];
        int pos = atomicAdd(&ofs[p.y - base], 1);
        ssrc[pbeg + pos] = p.x;
    }
}

// ---------------- prep: split x into bf16 hi/lo planes ----------------

__global__ void split_x(const float* __restrict__ x, ushort* __restrict__ xhi,
                        ushort* __restrict__ xlo, int total4) {
    int i = blockIdx.x * blockDim.x + threadIdx.x;
    if (i >= total4) return;
    float4 v = reinterpret_cast<const float4*>(x)[i];
    ushort4 h, l;
    float* vp = &v.x;
    ushort* hp = &h.x;
    ushort* lp = &l.x;
#pragma unroll
    for (int j = 0; j < 4; ++j) {
        unsigned hb = bf16rne(vp[j]);
        hp[j] = (ushort)hb;
        lp[j] = (ushort)bf16rne(vp[j] - bf16tof(hb));
    }
    reinterpret_cast<ushort4*>(xhi)[i] = h;
    reinterpret_cast<ushort4*>(xlo)[i] = l;
}

// ---------------- prep: pack [Wl|Wr] into MFMA B-fragment order ----------------
// b-frag (s = k/32, f = col/16): lane l, elem j holds W[s*32 + (l>>4)*8 + j][f*16 + (l&15)]
// packed linearly: pos = ((s*16 + f)*64 + lane)*8 + j   (ushort)

__global__ void pack_W(const float* __restrict__ Wl, const float* __restrict__ Wr,
                       ushort* __restrict__ Bhi, ushort* __restrict__ Blo, int K) {
    int tid = blockIdx.x * blockDim.x + threadIdx.x;
    if (tid >= K * 256) return;
    int k = tid >> 8;
    int c = tid & 255;
    float w = (c < 128) ? Wl[k * 128 + c] : Wr[k * 128 + (c - 128)];
    int s = k >> 5, kin = k & 31, kgrp = kin >> 3, j = kin & 7;
    int f = c >> 4, cin = c & 15;
    int lane = kgrp * 16 + cin;
    size_t pos = ((size_t)(s * 16 + f) * 64 + lane) * 8 + j;
    unsigned hb = bf16rne(w);
    Bhi[pos] = (ushort)hb;
    Blo[pos] = (ushort)bf16rne(w - bf16tof(hb));
}

// ---------------- MFMA GEMM: [xl|xr] = A @ [Wl|Wr] + [bl|br] ----------------
// grid = (row-tiles, 2 N-halves). Block = 4 waves, tile 64 rows x 128 cols.
// B staged in LDS (32KB -> 4 blocks/CU), read via ds_read_b128.
// Split-bf16: acc += alo*bhi + ahi*blo + ahi*bhi.
// half 0 writes xl as a SINGLE bf16 plane (gat_agg gathers it); half 1
// writes xr as f32 (read once, sequential).

template<int K>
__global__ __launch_bounds__(256) void gemm_mfma(
    const ushort* __restrict__ Ahi, const ushort* __restrict__ Alo,
    const ushort* __restrict__ Bhi, const ushort* __restrict__ Blo,
    const float* __restrict__ bl, const float* __restrict__ br,
    ushort* __restrict__ xlb, float* __restrict__ xr, int n)
{
    __shared__ ushort BshH[2 * 8 * 64 * 8];   // [ss][fl][lane][j] 16KB
    __shared__ ushort BshL[2 * 8 * 64 * 8];   // 16KB
    const int t = threadIdx.x;
    const int w = t >> 6;
    const int lane = t & 63;
    const int half = blockIdx.y;              // 0 -> xl cols, 1 -> xr cols
    const int r0 = blockIdx.x * 64 + w * 16;
    const int rl = lane & 15;
    const int kg = lane >> 4;
    int arow = r0 + rl; if (arow >= n) arow = 0;   // clamp loads; stores guarded

    const float4* __restrict__ gH = reinterpret_cast<const float4*>(Bhi);
    const float4* __restrict__ gL = reinterpret_cast<const float4*>(Blo);
    float4* __restrict__ sH = reinterpret_cast<float4*>(BshH);
    float4* __restrict__ sL = reinterpret_cast<float4*>(BshL);

    f32x4 acc[8];
#pragma unroll
    for (int f = 0; f < 8; ++f) acc[f] = (f32x4){0.f, 0.f, 0.f, 0.f};

#pragma unroll
    for (int sg = 0; sg < K / 64; ++sg) {
        if (sg) __syncthreads();
        // stage s = 2sg, 2sg+1 for this block's 8 col-frags
#pragma unroll
        for (int i = t; i < 1024; i += 256) {
            int ss = i >> 9, fl = (i >> 6) & 7, ln = i & 63;
            int gidx = ((2 * sg + ss) * 16 + half * 8 + fl) * 64 + ln;
            sH[i] = gH[gidx];
            sL[i] = gL[gidx];
        }
        __syncthreads();

#pragma unroll
        for (int ss = 0; ss < 2; ++ss) {
            const int s = 2 * sg + ss;
            const size_t ao = (size_t)arow * K + s * 32 + kg * 8;
            bfrag ahi = *reinterpret_cast<const bfrag*>(&Ahi[ao]);
            bfrag alo = *reinterpret_cast<const bfrag*>(&Alo[ao]);
#pragma unroll
            for (int fl = 0; fl < 8; ++fl) {
                const int lofs = ((ss * 8 + fl) * 64 + lane) * 8;
                bfrag bhi = *reinterpret_cast<const bfrag*>(&BshH[lofs]);
                bfrag blo = *reinterpret_cast<const bfrag*>(&BshL[lofs]);
                acc[fl] = __builtin_amdgcn_mfma_f32_16x16x32_bf16(alo, bhi, acc[fl], 0, 0, 0);
                acc[fl] = __builtin_amdgcn_mfma_f32_16x16x32_bf16(ahi, blo, acc[fl], 0, 0, 0);
                acc[fl] = __builtin_amdgcn_mfma_f32_16x16x32_bf16(ahi, bhi, acc[fl], 0, 0, 0);
            }
        }
    }

    // D layout: col = fl*16 + (lane&15), row = r0 + (lane>>4)*4 + j
    const int cin = lane & 15;
    const float* __restrict__ bias_ = half ? br : bl;
#pragma unroll
    for (int fl = 0; fl < 8; ++fl) {
        const int cc = fl * 16 + cin;
        const float bv = bias_[cc];
#pragma unroll
        for (int j = 0; j < 4; ++j) {
            const int rr = r0 + kg * 4 + j;
            if (rr < n) {
                const float v = acc[fl][j] + bv;
                if (half) xr[(size_t)rr * 128 + cc] = v;
                else      xlb[(size_t)rr * 128 + cc] = (ushort)bf16rne(v);
            }
        }
    }
}

// ---------------- fused per-destination GATv2 aggregation ----------------
// One node per wave, TWO EDGES PER WAVE-PASS: lanes 0-31 process edge A,
// lanes 32-63 edge B. Lane owns 4 channels (uint2 = 2x bf16-pair, 8B gather,
// 256B/edge unchanged). Head = 8-lane group -> 3-step DPP rowsum8. Halves
// combined once per node via shfl_xor(32). Tail/self handled by a per-half
// validity mask on ex. ~19 wave-instrs/edge vs round-6's ~25 (VALU-bound).

template<int OUTMODE>
__global__ __launch_bounds__(256) void gat_agg(
    const ushort* __restrict__ xlb, const float* __restrict__ xr,
    const float* __restrict__ att, const float* __restrict__ bias,
    const int* __restrict__ rowptr, const int* __restrict__ ssrc,
    float* __restrict__ out, ushort* __restrict__ ohi, ushort* __restrict__ olo,
    int n)
{
    const int node = blockIdx.x * 4 + (threadIdx.x >> 6);
    if (node >= n) return;
    const int lane = threadIdx.x & 63;
    const int m = lane & 31;
    const bool hiHalf = lane >= 32;

    const uint2* __restrict__ xlu = reinterpret_cast<const uint2*>(xlb);
    const float4 a4  = reinterpret_cast<const float4*>(att)[m];
    const float4 xrv = reinterpret_cast<const float4*>(xr)[(size_t)node * 32 + m];

    float den = 0.f;
    float4 acc = make_float4(0.f, 0.f, 0.f, 0.f);

#define GATHER(sA, sB) xlu[(size_t)(hiHalf ? (sB) : (sA)) * 32 + m]
#define PAIR(u, MSK)                                                  \
    {                                                                 \
        const float x0 = __uint_as_float((u).x << 16);                \
        const float x1 = __uint_as_float((u).x & 0xFFFF0000u);        \
        const float x2 = __uint_as_float((u).y << 16);                \
        const float x3 = __uint_as_float((u).y & 0xFFFF0000u);        \
        float e0 = x0 + xrv.x, e1 = x1 + xrv.y;                       \
        float e2 = x2 + xrv.z, e3 = x3 + xrv.w;                       \
        e0 = e0 > 0.f ? e0 : LEAKY * e0;                              \
        e1 = e1 > 0.f ? e1 : LEAKY * e1;                              \
        e2 = e2 > 0.f ? e2 : LEAKY * e2;                              \
        e3 = e3 > 0.f ? e3 : LEAKY * e3;                              \
        float p = e0 * a4.x + e1 * a4.y + e2 * a4.z + e3 * a4.w;      \
        p = rowsum8(p);                                               \
        float ex = __expf(p) MSK;                                     \
        den += ex;                                                    \
        acc.x += ex * x0; acc.y += ex * x1;                           \
        acc.z += ex * x2; acc.w += ex * x3;                           \
    }

    int i = rowptr[node];
    const int end = rowptr[node + 1];

    // pass 0: self-loop (half A) + first real edge (half B, if any)
    {
        const bool vB = i < end;
        const int sB = vB ? ssrc[i] : node;
        uint2 u = GATHER(node, sB);
        const float msk = (hiHalf && !vB) ? 0.f : 1.f;
        PAIR(u, * msk);
        if (vB) ++i;
    }

    for (; i + 8 <= end; i += 8) {
        int s0 = ssrc[i],     s1 = ssrc[i + 1], s2 = ssrc[i + 2], s3 = ssrc[i + 3];
        int s4 = ssrc[i + 4], s5 = ssrc[i + 5], s6 = ssrc[i + 6], s7 = ssrc[i + 7];
        uint2 u0 = GATHER(s0, s1);
        uint2 u1 = GATHER(s2, s3);
        uint2 u2 = GATHER(s4, s5);
        uint2 u3 = GATHER(s6, s7);
        PAIR(u0, );
        PAIR(u1, );
        PAIR(u2, );
        PAIR(u3, );
    }
    for (; i + 2 <= end; i += 2) {
        int s0 = ssrc[i], s1 = ssrc[i + 1];
        uint2 u = GATHER(s0, s1);
        PAIR(u, );
    }
    if (i < end) {
        int s0 = ssrc[i];
        uint2 u = GATHER(s0, s0);
        const float msk = hiHalf ? 0.f : 1.f;
        PAIR(u, * msk);
    }
#undef PAIR
#undef GATHER

    // combine the two halves (each half covered all 128 channels of its edges)
    den   += __shfl_xor(den,   32);
    acc.x += __shfl_xor(acc.x, 32);
    acc.y += __shfl_xor(acc.y, 32);
    acc.z += __shfl_xor(acc.z, 32);
    acc.w += __shfl_xor(acc.w, 32);

    if (!hiHalf) {
        const float4 b4 = reinterpret_cast<const float4*>(bias)[m];
        const float r = 1.f / den;
        const float o0 = fmaxf(acc.x * r + b4.x, 0.f);
        const float o1 = fmaxf(acc.y * r + b4.y, 0.f);
        const float o2 = fmaxf(acc.z * r + b4.z, 0.f);
        const float o3 = fmaxf(acc.w * r + b4.w, 0.f);
        if (OUTMODE == 0) {
            reinterpret_cast<float4*>(out)[(size_t)node * 32 + m] =
                make_float4(o0, o1, o2, o3);
        } else {
            unsigned h0 = bf16rne(o0), h1 = bf16rne(o1);
            unsigned h2 = bf16rne(o2), h3 = bf16rne(o3);
            ushort4 hv = make_ushort4((ushort)h0, (ushort)h1, (ushort)h2, (ushort)h3);
            ushort4 lv = make_ushort4((ushort)bf16rne(o0 - bf16tof(h0)),
                                      (ushort)bf16rne(o1 - bf16tof(h1)),
                                      (ushort)bf16rne(o2 - bf16tof(h2)),
                                      (ushort)bf16rne(o3 - bf16tof(h3)));
            reinterpret_cast<ushort4*>(ohi)[(size_t)node * 32 + m] = hv;
            reinterpret_cast<ushort4*>(olo)[(size_t)node * 32 + m] = lv;
        }
    }
}

// ---------------- launch ----------------

extern "C" void kernel_launch(void* const* d_in, const int* in_sizes, int n_in,
                              void* d_out, int out_size, void* d_ws, size_t ws_size,
                              hipStream_t stream)
{
    const float* x     = (const float*)d_in[0];
    const float* Wl1   = (const float*)d_in[1];
    const float* bl1   = (const float*)d_in[2];
    const float* Wr1   = (const float*)d_in[3];
    const float* br1   = (const float*)d_in[4];
    const float* att1  = (const float*)d_in[5];
    const float* bias1 = (const float*)d_in[6];
    const float* Wl2   = (const float*)d_in[7];
    const float* bl2   = (const float*)d_in[8];
    const float* Wr2   = (const float*)d_in[9];
    const float* br2   = (const float*)d_in[10];
    const float* att2  = (const float*)d_in[11];
    const float* bias2 = (const float*)d_in[12];
    const int*   eidx  = (const int*)d_in[13];

    const int n = in_sizes[0] / 64;
    const int E = in_sizes[13] / 2;
    const int* src = eidx;
    const int* dst = eidx + E;
    const int nb = (n + 255) >> 8;        // 196 buckets

    char* ws = (char*)d_ws;
    size_t off = 0;
    auto alloc = [&](size_t bytes) -> void* {
        void* p = ws + off;
        off = (off + bytes + 255) & ~(size_t)255;
        return p;
    };
    int* rowptr   = (int*)alloc((size_t)(n + 1) * 4);
    int* ssrc     = (int*)alloc((size_t)E * 4);
    int* bcnt     = (int*)alloc((size_t)nb * 4);
    int* bbase    = (int*)alloc((size_t)(nb + 1) * 4);
    int* gwoff    = (int*)alloc((size_t)nb * 4);
    ushort* B1hi  = (ushort*)alloc((size_t)64  * 256 * 2);
    ushort* B1lo  = (ushort*)alloc((size_t)64  * 256 * 2);
    ushort* B2hi  = (ushort*)alloc((size_t)128 * 256 * 2);
    ushort* B2lo  = (ushort*)alloc((size_t)128 * 256 * 2);
    // X region: xhi1/xlo1 (layer-1 A) live first; after gemm1 consumes them,
    // agg1 overwrites the region with hhi/hlo.
    ushort* xreg  = (ushort*)alloc((size_t)n * 128 * 2 * 2);
    ushort* xhi1  = xreg;
    ushort* xlo1  = xreg + (size_t)n * 64;
    ushort* hhi   = xreg;
    ushort* hlo   = xreg + (size_t)n * 128;
    ushort* xlb   = (ushort*)alloc((size_t)n * 128 * 2);   // bf16 xl plane
    float* xrbuf  = (float*)alloc((size_t)n * 128 * 4);
    // pairs (E * 8B = 6.8MB) aliases xlb (12.8MB): consumed by bucket_sort
    // strictly before gemm1 writes xlb.
    int2* pairs   = (int2*)xlb;
    float* outp   = (float*)d_out;

    // ---- CSR build: bucketed multisplit ----
    hipMemsetAsync(bcnt, 0, (size_t)nb * 4, stream);
    bucket_hist<<<128, 256, 0, stream>>>(dst, bcnt, E, nb);
    bucket_scan<<<1, 256, 0, stream>>>(bcnt, bbase, gwoff, rowptr, E, nb, n);
    multisplit<<<(E + TILE - 1) / TILE, 256, 0, stream>>>(src, dst, gwoff, pairs, E, nb);
    bucket_sort<<<nb, 256, 0, stream>>>(pairs, bbase, rowptr, ssrc, n);

    // ---- prep: bf16 hi/lo splits ----
    const int total4 = n * 64 / 4;
    split_x<<<(total4 + 255) / 256, 256, 0, stream>>>(x, xhi1, xlo1, total4);
    pack_W<<<(64  * 256 + 255) / 256, 256, 0, stream>>>(Wl1, Wr1, B1hi, B1lo, 64);
    pack_W<<<(128 * 256 + 255) / 256, 256, 0, stream>>>(Wl2, Wr2, B2hi, B2lo, 128);

    const dim3 ggrid((n + 63) / 64, 2);

    // ---- layer 1 ----
    gemm_mfma<64><<<ggrid, 256, 0, stream>>>(xhi1, xlo1, B1hi, B1lo, bl1, br1,
                                             xlb, xrbuf, n);
    gat_agg<1><<<(n + 3) / 4, 256, 0, stream>>>(xlb, xrbuf, att1, bias1, rowptr, ssrc,
                                                nullptr, hhi, hlo, n);

    // ---- layer 2 ----
    gemm_mfma<128><<<ggrid, 256, 0, stream>>>(hhi, hlo, B2hi, B2lo, bl2, br2,
                                              xlb, xrbuf, n);
    gat_agg<0><<<(n + 3) / 4, 256, 0, stream>>>(xlb, xrbuf, att2, bias2, rowptr, ssrc,
                                                outp, nullptr, nullptr, n);
}